// Round 11
// baseline (3432.704 us; speedup 1.0000x reference)
//
#include <hip/hip_runtime.h>
#include <hip/hip_bf16.h>
#include <stdint.h>

// Sparse autoencoder: z1 = x@W^T + b_enc ; top-k(3276) mask ; z2 = a1@W + b_dec
// Encoder = single fp16 MFMA GEMM (approx, sigma ~4e-4); exact top-k selection
// via fp32 band recompute near the threshold (h-major, W streamed once, fp32 x
// L3-resident). GEMMs: proven 128^2 m97-structure + T2 swizzle, XCD-chunked
// grid, per-GEMM supertile sized to fit L3 (decoder K=32768 strips are 8.4 MB
// per block -> 16x8 supertile = 202 MB working set; 16x32 thrashed at 403 MB).

#define DIM      4096
#define BATCH    4096
#define NROWS_W  32768
#define KCNT     3276
#define DELTA    0.0025f
#define ROWCAP   256
#define HCAP     64
#define CANDCAP  3584

typedef _Float16 f16x8 __attribute__((ext_vector_type(8)));
typedef _Float16 f16x4 __attribute__((ext_vector_type(4)));
typedef float    f32x4 __attribute__((ext_vector_type(4)));

__device__ __forceinline__ void gload_lds16(const void* g, void* l) {
  __builtin_amdgcn_global_load_lds(
      (const __attribute__((address_space(1))) void*)g,
      (__attribute__((address_space(3))) void*)l, 16, 0, 0);
}

// ---------------- x: fp32 -> fp16 (encoder A operand) ----------------
__global__ void k_cvtx(const float* __restrict__ s, _Float16* __restrict__ hi, int n4) {
  int i = blockIdx.x * 256 + threadIdx.x;
  const int stride = gridDim.x * 256;
  for (; i < n4; i += stride) {
    f32x4 v = ((const f32x4*)s)[i];
    f16x4 h;
#pragma unroll
    for (int j = 0; j < 4; ++j) h[j] = (_Float16)v[j];
    ((f16x4*)hi)[i] = h;
  }
}

// --- fused W convert+transpose: W fp32 -> Wh fp16 [H,D] + Wt fp16 [D,H] ------
// Also zeroes bcnt (blockIdx.y==0 blocks) to save a launch.
__global__ void k_splitw(const float* __restrict__ W, _Float16* __restrict__ Wh,
                         _Float16* __restrict__ Wt, f32x4* __restrict__ bcntv) {
  __shared__ _Float16 t[64][65];
  const int c0 = blockIdx.x * 64, r0 = blockIdx.y * 64;
  const int tx = threadIdx.x, ty = threadIdx.y;  // (64, 8)
  if (blockIdx.y == 0) {
    const int idx = blockIdx.x * 512 + ty * 64 + tx;
    if (idx < 8192) {  // 128 KB bcnt
      f32x4 z = {0.f, 0.f, 0.f, 0.f};
      bcntv[idx] = z;
    }
  }
  for (int rr = ty; rr < 64; rr += 8) {
    const float w = W[(long)(r0 + rr) * DIM + c0 + tx];
    const _Float16 h = (_Float16)w;
    Wh[(long)(r0 + rr) * DIM + c0 + tx] = h;
    t[rr][tx] = h;
  }
  __syncthreads();
  for (int cc = ty; cc < 64; cc += 8)
    Wt[(long)(c0 + cc) * NROWS_W + r0 + tx] = t[tx][cc];
}

// ---------------- GEMM: C[M,N] = A[M,K] * B^T[N,K] + bias (proven R3) --------
// T2 XOR-swizzled LDS. XCD chunk remap + (2^SML x 2^SNL) supertile remap.
template <int MT, int NTOT, int KT, int SML, int SNL>
__global__ __launch_bounds__(256, 2)
void k_gemm(const _Float16* __restrict__ A, const _Float16* __restrict__ B,
            const float* __restrict__ bias, float* __restrict__ C) {
  constexpr int BM = 128, BN = 128, BK = 64;
  __shared__ __align__(16) _Float16 sA[BM * BK];
  __shared__ __align__(16) _Float16 sB[BN * BK];

  const int tid = threadIdx.x;
  constexpr int nbm = MT / BM, nbn = NTOT / BN;
  constexpr int grid = nbm * nbn;
  constexpr int nstn = nbn >> SNL;
  constexpr int stsz = 1 << (SML + SNL);

  int wg = blockIdx.x;
  wg = (wg & 7) * (grid >> 3) + (wg >> 3);  // XCD chunk (grid % 8 == 0)
  const int g = wg >> (SML + SNL), r = wg & (stsz - 1);
  const int bm = ((g / nstn) << SML) + (r >> SNL);
  const int bn = ((g % nstn) << SNL) + (r & ((1 << SNL) - 1));

  const int m0 = bm * BM, n0 = bn * BN;
  const int lane = tid & 63, wid = tid >> 6;
  const int wm = wid >> 1, wn = wid & 1;
  const int lr = lane & 15, lk = lane >> 4;
  const int swz = (lr & 7) << 4;

  f32x4 acc[4][4] = {};

  for (int k0 = 0; k0 < KT; k0 += BK) {
#pragma unroll
    for (int rr = 0; rr < 4; ++rr) {
      const int o = (rr * 256 + tid) * 16;
      const int row = o >> 7;
      const int colb = (o & 127) ^ ((row & 7) << 4);
      const long gA = ((long)(m0 + row) * KT + k0) * 2 + colb;
      const long gB = ((long)(n0 + row) * KT + k0) * 2 + colb;
      gload_lds16((const char*)A + gA, (char*)sA + o);
      gload_lds16((const char*)B + gB, (char*)sB + o);
    }
    __syncthreads();

#pragma unroll
    for (int kk = 0; kk < 2; ++kk) {
      f16x8 va[4], vb[4];
      const int kbase = (kk * 64 + lk * 16) ^ swz;
#pragma unroll
      for (int m = 0; m < 4; ++m) {
        const int row = wm * 64 + m * 16 + lr;
        va[m] = *(const f16x8*)((const char*)sA + row * 128 + kbase);
      }
#pragma unroll
      for (int n = 0; n < 4; ++n) {
        const int row = wn * 64 + n * 16 + lr;
        vb[n] = *(const f16x8*)((const char*)sB + row * 128 + kbase);
      }
#pragma unroll
      for (int m = 0; m < 4; ++m)
#pragma unroll
        for (int n = 0; n < 4; ++n)
          acc[m][n] = __builtin_amdgcn_mfma_f32_16x16x32_f16(va[m], vb[n], acc[m][n], 0, 0, 0);
    }
    __syncthreads();
  }

  // C/D layout: col = lane&15, row = (lane>>4)*4 + reg
#pragma unroll
  for (int n = 0; n < 4; ++n) {
    const int col = n0 + wn * 64 + n * 16 + lr;
    const float bv = bias[col];
#pragma unroll
    for (int m = 0; m < 4; ++m) {
      const int r0r = m0 + wm * 64 + m * 16 + lk * 4;
#pragma unroll
      for (int j = 0; j < 4; ++j)
        C[(long)(r0r + j) * NTOT + col] = acc[m][n][j] + bv;
    }
  }
}

// ---------------- float <-> order-preserving u32 ----------------
__device__ __forceinline__ unsigned f2o(float f) {
  unsigned b = __float_as_uint(f);
  return ((int)b < 0) ? ~b : (b | 0x80000000u);
}
__device__ __forceinline__ float o2f(unsigned u) {
  unsigned b = (u & 0x80000000u) ? (u & 0x7FFFFFFFu) : ~u;
  return __uint_as_float(b);
}

// --- per-row: threshold + band + bulk a1 write, 2 z1 streams total -----------
// pass A: 4096-bin hist -> binsel + c_above(bins >= binsel+2, all > t+delta).
// pass B: one z1 stream: writes a1 (upper bins -> v, lower -> 0, cand bins ->
// 0 placeholder) and collects cands (bins binsel-1..binsel+1) to LDS + global.
// Then in-LDS 20-bit refine -> t; band members from LDS cands.
// k_select later patches cand members with v > t+delta and band winners.
__global__ __launch_bounds__(256)
void k_topk4(const float* __restrict__ z1, float* __restrict__ thr,
             unsigned* __restrict__ rowlist, unsigned* __restrict__ rowcnt,
             unsigned* __restrict__ c1, unsigned* __restrict__ bucket,
             unsigned* __restrict__ bcnt, _Float16* __restrict__ a1,
             float* __restrict__ candv, unsigned short* __restrict__ candi,
             unsigned* __restrict__ candn, int kwant) {
  __shared__ unsigned hist[4096];
  __shared__ float cv[CANDCAP];
  __shared__ unsigned short ci[CANDCAP];
  __shared__ unsigned s_n, s_bin, s_rem, s_wt[4], s_cnt, s_above;
  const int tid = threadIdx.x;
  const int b = blockIdx.x;
  const f32x4* zv = (const f32x4*)(z1 + (long)b * NROWS_W);
  constexpr int NV = NROWS_W / 4;

  // ---- pass A: 4096-bin histogram (top 12 bits) ----
#pragma unroll
  for (int j = 0; j < 16; ++j) hist[tid + j * 256] = 0;
  if (tid == 0) { s_n = 0; s_cnt = 0; s_above = 0; }
  __syncthreads();
  for (int i = tid; i < NV; i += 256) {
    f32x4 v = zv[i];
#pragma unroll
    for (int j = 0; j < 4; ++j) atomicAdd(&hist[f2o(v[j]) >> 20], 1u);
  }
  __syncthreads();
  unsigned p = 0;
#pragma unroll
  for (int j = 0; j < 16; ++j) p += hist[tid * 16 + j];
  unsigned sfx = p;
  const int lane = tid & 63, w = tid >> 6;
#pragma unroll
  for (int off = 1; off < 64; off <<= 1) {
    unsigned o = __shfl_down(sfx, off);
    sfx += (lane + off < 64) ? o : 0u;
  }
  if (lane == 0) s_wt[w] = sfx;
  __syncthreads();
  unsigned above_waves = 0;
  for (int ww = w + 1; ww < 4; ++ww) above_waves += s_wt[ww];
  const unsigned incl = sfx + above_waves;
  const int cnt = __syncthreads_count(incl >= (unsigned)kwant);
  const int tstar = cnt - 1;
  if (tid == tstar) {
    unsigned cum = incl - p;
    int bsel = tid * 16;
    for (int j = 15; j >= 0; --j) {
      const unsigned h = hist[tid * 16 + j];
      if (cum + h >= (unsigned)kwant) { bsel = tid * 16 + j; break; }
      cum += h;
    }
    s_bin = (unsigned)bsel;
    s_rem = (unsigned)kwant - cum;
  }
  __syncthreads();
  const unsigned binsel = s_bin;
  unsigned rem = s_rem;

  // c_above = count in bins >= binsel+2 (all guaranteed > t+DELTA: bin width
  // ~0.06..0.125 >> DELTA)
  {
    unsigned loc = 0;
#pragma unroll
    for (int j = 0; j < 16; ++j) {
      const unsigned bin = tid * 16 + j;
      if (bin >= binsel + 2) loc += hist[bin];
    }
    if (loc) atomicAdd(&s_above, loc);
  }

  // ---- pass B: write a1 bulk + collect cands (bins binsel-1..binsel+1) ----
  const unsigned blo = (binsel > 0) ? binsel - 1 : 0;
  const unsigned bhi = (binsel < 4095) ? binsel + 1 : 4095;
  f16x4* av = (f16x4*)(a1 + (long)b * NROWS_W);
  for (int i = tid; i < NV; i += 256) {
    f32x4 v = zv[i];
    f16x4 o;
#pragma unroll
    for (int j = 0; j < 4; ++j) {
      const unsigned bin = f2o(v[j]) >> 20;
      o[j] = (bin > bhi) ? (_Float16)v[j] : (_Float16)0.0f;
      if (bin >= blo && bin <= bhi) {
        const unsigned jj = atomicAdd(&s_n, 1u);
        if (jj < CANDCAP) { cv[jj] = v[j]; ci[jj] = (unsigned short)(i * 4 + j); }
      }
    }
    av[i] = o;
  }
  __syncthreads();
  const int n = (s_n < CANDCAP) ? (int)s_n : CANDCAP;
  if (tid == 0) candn[b] = (unsigned)n;
  for (int i = tid; i < n; i += 256) {  // mirror cands to global for k_select
    candv[(long)b * CANDCAP + i] = cv[i];
    candi[(long)b * CANDCAP + i] = ci[i];
  }

  // ---- in-LDS 20-bit refine over cand members of binsel ----
  unsigned pfx = 0;
#pragma unroll
  for (int pass = 0; pass < 3; ++pass) {
    const int shift = (pass == 0) ? 12 : (pass == 1) ? 4 : 0;
    const int nb = (pass == 2) ? 16 : 256;
    if (tid < 256) hist[tid] = 0;
    __syncthreads();
    for (int i = tid; i < n; i += 256) {
      const unsigned u = f2o(cv[i]);
      if ((u >> 20) != binsel) continue;
      const unsigned v = u & 0xFFFFFu;
      const bool m = (pass == 0) ? true
                     : (pass == 1) ? ((v >> 12) == (pfx >> 12))
                                   : ((v >> 4) == (pfx >> 4));
      if (m) atomicAdd(&hist[(v >> shift) & (nb - 1)], 1u);
    }
    __syncthreads();
    if (tid == 0) {
      unsigned cum = 0;
      int d = nb - 1;
      for (; d > 0; --d) {
        if (cum + hist[d] >= rem) break;
        cum += hist[d];
      }
      s_bin = (unsigned)d;
      s_rem = rem - cum;
    }
    __syncthreads();
    pfx |= (s_bin << shift);
    rem = s_rem;
    __syncthreads();
  }
  const float t = o2f((binsel << 20) | pfx);
  if (tid == 0) thr[b] = t;
  const float hi = t + DELTA, lo = t - DELTA;

  // ---- band members from LDS cand list ----
  for (int i = tid; i < n; i += 256) {
    const float v = cv[i];
    if (v >= lo && v <= hi) {
      const unsigned idx = ci[i];
      const unsigned jj = atomicAdd(&s_cnt, 1u);
      if (jj < ROWCAP) {
        rowlist[(long)b * ROWCAP + jj] = idx;
        const unsigned pq = atomicAdd(&bcnt[idx], 1u);
        if (pq < HCAP) bucket[(long)idx * HCAP + pq] = ((unsigned)b << 9) | jj;
      }
    }
  }
  __syncthreads();
  if (tid == 0) {
    rowcnt[b] = (s_cnt < ROWCAP) ? s_cnt : ROWCAP;
    c1[b] = s_above;  // count of sure-ins OUTSIDE the cand bins
  }
}

// -------- h-major exact recompute: fp32 W row in LDS, fp32 x (L3) ----------
__global__ void k_recompute(const float* __restrict__ W, const float* __restrict__ x,
                            const unsigned* __restrict__ bucket,
                            const unsigned* __restrict__ bcnt,
                            float* __restrict__ exact) {
  const int h = blockIdx.x;
  unsigned n = bcnt[h];
  if (n > HCAP) n = HCAP;
  if (n == 0) return;
  __shared__ float wrec[DIM];
  const long wb = (long)h * DIM;
  for (int i = threadIdx.x; i < DIM / 4; i += 256)
    ((f32x4*)wrec)[i] = ((const f32x4*)(W + wb))[i];
  __syncthreads();
  const int w = threadIdx.x >> 6, lane = threadIdx.x & 63;
  for (unsigned e = w; e < n; e += 4) {
    const unsigned ent = bucket[(long)h * HCAP + e];
    const int b = ent >> 9, j = ent & 511;
    const f32x4* xv = (const f32x4*)(x + (long)b * DIM);
    float s = 0.f;
#pragma unroll
    for (int c = 0; c < 16; ++c) {
      const int i4 = c * 64 + lane;
      f32x4 v = xv[i4];
      const float* wr = &wrec[i4 * 4];
#pragma unroll
      for (int q = 0; q < 4; ++q) s += v[q] * wr[q];
    }
#pragma unroll
    for (int m = 32; m; m >>= 1) s += __shfl_xor(s, m);
    if (lane == 0) exact[(long)b * ROWCAP + j] = s;
  }
}

// -- per-row: c1 finalize, band rank-select, patch cand region of a1 ---------
__global__ void k_select(const float* __restrict__ exact, const unsigned* __restrict__ rowlist,
                         const unsigned* __restrict__ rowcnt, const unsigned* __restrict__ c1,
                         const float* __restrict__ thr, const float* __restrict__ candv,
                         const unsigned short* __restrict__ candi,
                         const unsigned* __restrict__ candn,
                         const float* __restrict__ z1, _Float16* __restrict__ a1) {
  const int b = blockIdx.x;
  const int n = (int)rowcnt[b];
  const int nc = (int)candn[b];
  const float t = thr[b];
  const float hi = t + DELTA;
  __shared__ float vals[ROWCAP];
  __shared__ unsigned s_c;
  const int j = threadIdx.x;  // blockDim == ROWCAP == 256
  if (j == 0) s_c = 0;
  vals[j] = (j < n) ? exact[(long)b * ROWCAP + j] : -1e30f;
  __syncthreads();
  // sure-ins inside cand bins
  unsigned loc = 0;
  for (int i = j; i < nc; i += 256) loc += (candv[(long)b * CANDCAP + i] > hi) ? 1u : 0u;
  if (loc) atomicAdd(&s_c, loc);
  __syncthreads();
  const int need = KCNT - (int)c1[b] - (int)s_c;
  // band rank-select -> write winners
  if (j < n) {
    const float vj = vals[j];
    int rank = 0;
    for (int i = 0; i < n; ++i) {
      const float vi = vals[i];
      rank += (vi > vj || (vi == vj && i < j)) ? 1 : 0;
    }
    if (rank < need) {
      const unsigned h = rowlist[(long)b * ROWCAP + j];
      const long off = (long)b * NROWS_W + h;
      a1[off] = (_Float16)z1[off];
    }
  }
  // patch cand sure-ins (placeholder 0 -> value)
  for (int i = j; i < nc; i += 256) {
    const float v = candv[(long)b * CANDCAP + i];
    if (v > hi) a1[(long)b * NROWS_W + candi[(long)b * CANDCAP + i]] = (_Float16)v;
  }
}

extern "C" void kernel_launch(void* const* d_in, const int* in_sizes, int n_in,
                              void* d_out, int out_size, void* d_ws, size_t ws_size,
                              hipStream_t stream) {
  const float* x     = (const float*)d_in[0];
  const float* W     = (const float*)d_in[1];
  const float* b_enc = (const float*)d_in[2];
  const float* b_dec = (const float*)d_in[3];
  float* out = (float*)d_out;

  const long NW = (long)NROWS_W * DIM;    // 134217728
  const long NX = (long)BATCH * DIM;      // 16777216
  const long NZ = (long)BATCH * NROWS_W;  // 134217728

  char* ws = (char*)d_ws;
  _Float16* Wh = (_Float16*)ws;    // 2*NW  (dead after encoder -> reused as a1)
  _Float16* Wt = Wh + NW;          // 2*NW
  _Float16* xh = Wt + NW;          // 2*NX
  float*  z1 = (float*)(xh + NX);  // 4*NZ
  float*  thr = z1 + NZ;           // 4*BATCH
  char*   sc = (char*)(thr + BATCH);
  unsigned* rowcnt  = (unsigned*)sc;                     // 16 KB
  unsigned* c1      = (unsigned*)(sc + 16384);           // 16 KB
  unsigned* bcnt    = (unsigned*)(sc + 32768);           // 128 KB (zeroed in splitw)
  float*    exact   = (float*)(sc + 163840);             // 4 MB
  unsigned* rowlist = (unsigned*)(sc + 4358144);         // 4 MB
  unsigned* bucket  = (unsigned*)(sc + 8552448);         // 8 MB
  unsigned* candn   = (unsigned*)(sc + 16941056);        // 16 KB
  float*    candv   = (float*)(sc + 16957440);           // 58.7 MB
  unsigned short* candi = (unsigned short*)(sc + 75677696);  // 29.4 MB (end ~105 MB)
  _Float16* a1 = Wh;

  const size_t needed = (size_t)(4 * NW + 2 * NX) + (size_t)4 * NZ + 4 * BATCH + 106000000;
  if (ws_size < needed) return;

  k_splitw<<<dim3(DIM / 64, NROWS_W / 64), dim3(64, 8), 0, stream>>>(W, Wh, Wt, (f32x4*)bcnt);
  k_cvtx<<<2048, 256, 0, stream>>>(x, xh, (int)(NX / 4));

  // encoder (approx): z1 = xh @ Wh^T + b_enc; supertile 16x32 (50 MB, L3-fits)
  k_gemm<BATCH, NROWS_W, DIM, 4, 5>
      <<<(BATCH / 128) * (NROWS_W / 128), 256, 0, stream>>>(xh, Wh, b_enc, z1);

  k_topk4<<<BATCH, 256, 0, stream>>>(z1, thr, rowlist, rowcnt, c1, bucket, bcnt,
                                     a1, candv, candi, candn, KCNT);
  k_recompute<<<NROWS_W, 256, 0, stream>>>(W, x, bucket, bcnt, exact);
  k_select<<<BATCH, ROWCAP, 0, stream>>>(exact, rowlist, rowcnt, c1, thr,
                                         candv, candi, candn, z1, a1);

  // decoder: out = a1 @ W + b_dec (B^T = Wt); K=32768 -> 8.4 MB strips ->
  // supertile 16x8 (202 MB working set, fits L3; 16x32 was 403 MB -> thrash)
  k_gemm<BATCH, DIM, NROWS_W, 4, 3>
      <<<(BATCH / 128) * (DIM / 128), 256, 0, stream>>>(a1, Wt, b_dec, out);
}

// Round 12
// 3159.296 us; speedup vs baseline: 1.0865x; 1.0865x over previous
//
#include <hip/hip_runtime.h>
#include <hip/hip_bf16.h>
#include <hip/hip_fp16.h>
#include <stdint.h>

// Sparse autoencoder: z1 = x@W^T + b_enc ; top-k(3276) mask ; z2 = a1@W + b_dec
// Encoder = single fp16 MFMA GEMM writing fp16 z1 (approx err < 0.003 incl
// rounding); exact top-k selection via fp32 band recompute near the threshold
// (h-major, W streamed once, fp32 x L3-resident). Threshold = exact k-th
// largest fp16 value via 4096-bin radix on 16-bit ordered keys + 16-way refine.
// GEMMs: proven 128^2 m97-structure + T2 swizzle + supertile remap on RAW
// blockIdx (R10 config; XCD chunking measured -14% in R11: co-residency spread
// across 8 supertiles -> 290 MB working set > L3).

#define DIM      4096
#define BATCH    4096
#define NROWS_W  32768
#define KCNT     3276
#define DELTA    0.005f
#define ROWCAP   256
#define HCAP     64
#define CANDCAP  512

typedef _Float16 f16x8 __attribute__((ext_vector_type(8)));
typedef _Float16 f16x4 __attribute__((ext_vector_type(4)));
typedef float    f32x4 __attribute__((ext_vector_type(4)));
typedef unsigned short u16x8 __attribute__((ext_vector_type(8)));

__device__ __forceinline__ void gload_lds16(const void* g, void* l) {
  __builtin_amdgcn_global_load_lds(
      (const __attribute__((address_space(1))) void*)g,
      (__attribute__((address_space(3))) void*)l, 16, 0, 0);
}

// ---------------- x: fp32 -> fp16 (encoder A operand) ----------------
__global__ void k_cvtx(const float* __restrict__ s, _Float16* __restrict__ hi, int n4) {
  int i = blockIdx.x * 256 + threadIdx.x;
  const int stride = gridDim.x * 256;
  for (; i < n4; i += stride) {
    f32x4 v = ((const f32x4*)s)[i];
    f16x4 h;
#pragma unroll
    for (int j = 0; j < 4; ++j) h[j] = (_Float16)v[j];
    ((f16x4*)hi)[i] = h;
  }
}

// --- fused W convert+transpose: W fp32 -> Wh fp16 [H,D] + Wt fp16 [D,H] ------
// Also zeroes bcnt (blockIdx.y==0 blocks) to save a launch.
__global__ void k_splitw(const float* __restrict__ W, _Float16* __restrict__ Wh,
                         _Float16* __restrict__ Wt, f32x4* __restrict__ bcntv) {
  __shared__ _Float16 t[64][65];
  const int c0 = blockIdx.x * 64, r0 = blockIdx.y * 64;
  const int tx = threadIdx.x, ty = threadIdx.y;  // (64, 8)
  if (blockIdx.y == 0) {
    const int idx = blockIdx.x * 512 + ty * 64 + tx;
    if (idx < 8192) {  // 128 KB bcnt
      f32x4 z = {0.f, 0.f, 0.f, 0.f};
      bcntv[idx] = z;
    }
  }
  for (int rr = ty; rr < 64; rr += 8) {
    const float w = W[(long)(r0 + rr) * DIM + c0 + tx];
    const _Float16 h = (_Float16)w;
    Wh[(long)(r0 + rr) * DIM + c0 + tx] = h;
    t[rr][tx] = h;
  }
  __syncthreads();
  for (int cc = ty; cc < 64; cc += 8)
    Wt[(long)(c0 + cc) * NROWS_W + r0 + tx] = t[tx][cc];
}

// ---------------- GEMM: C[M,N] = A[M,K] * B^T[N,K] + bias (proven R10) -------
// T2 XOR-swizzled LDS; (2^SML x 2^SNL) supertile remap on raw blockIdx.
template <int MT, int NTOT, int KT, int SML, int SNL, typename OutT>
__global__ __launch_bounds__(256, 2)
void k_gemm(const _Float16* __restrict__ A, const _Float16* __restrict__ B,
            const float* __restrict__ bias, OutT* __restrict__ C) {
  constexpr int BM = 128, BN = 128, BK = 64;
  __shared__ __align__(16) _Float16 sA[BM * BK];
  __shared__ __align__(16) _Float16 sB[BN * BK];

  const int tid = threadIdx.x;
  constexpr int nbn = NTOT / BN;
  constexpr int nstn = nbn >> SNL;
  constexpr int stsz = 1 << (SML + SNL);

  const int g = blockIdx.x >> (SML + SNL), r = blockIdx.x & (stsz - 1);
  const int bm = ((g / nstn) << SML) + (r >> SNL);
  const int bn = ((g % nstn) << SNL) + (r & ((1 << SNL) - 1));

  const int m0 = bm * BM, n0 = bn * BN;
  const int lane = tid & 63, wid = tid >> 6;
  const int wm = wid >> 1, wn = wid & 1;
  const int lr = lane & 15, lk = lane >> 4;
  const int swz = (lr & 7) << 4;

  f32x4 acc[4][4] = {};

  for (int k0 = 0; k0 < KT; k0 += BK) {
#pragma unroll
    for (int rr = 0; rr < 4; ++rr) {
      const int o = (rr * 256 + tid) * 16;
      const int row = o >> 7;
      const int colb = (o & 127) ^ ((row & 7) << 4);
      const long gA = ((long)(m0 + row) * KT + k0) * 2 + colb;
      const long gB = ((long)(n0 + row) * KT + k0) * 2 + colb;
      gload_lds16((const char*)A + gA, (char*)sA + o);
      gload_lds16((const char*)B + gB, (char*)sB + o);
    }
    __syncthreads();

#pragma unroll
    for (int kk = 0; kk < 2; ++kk) {
      f16x8 va[4], vb[4];
      const int kbase = (kk * 64 + lk * 16) ^ swz;
#pragma unroll
      for (int m = 0; m < 4; ++m) {
        const int row = wm * 64 + m * 16 + lr;
        va[m] = *(const f16x8*)((const char*)sA + row * 128 + kbase);
      }
#pragma unroll
      for (int n = 0; n < 4; ++n) {
        const int row = wn * 64 + n * 16 + lr;
        vb[n] = *(const f16x8*)((const char*)sB + row * 128 + kbase);
      }
#pragma unroll
      for (int m = 0; m < 4; ++m)
#pragma unroll
        for (int n = 0; n < 4; ++n)
          acc[m][n] = __builtin_amdgcn_mfma_f32_16x16x32_f16(va[m], vb[n], acc[m][n], 0, 0, 0);
    }
    __syncthreads();
  }

  // C/D layout: col = lane&15, row = (lane>>4)*4 + reg
#pragma unroll
  for (int n = 0; n < 4; ++n) {
    const int col = n0 + wn * 64 + n * 16 + lr;
    const float bv = bias[col];
#pragma unroll
    for (int m = 0; m < 4; ++m) {
      const int r0r = m0 + wm * 64 + m * 16 + lk * 4;
#pragma unroll
      for (int j = 0; j < 4; ++j)
        C[(long)(r0r + j) * NTOT + col] = (OutT)(acc[m][n][j] + bv);
    }
  }
}

// ------------- fp16 bits <-> order-preserving 16-bit key ----------------
__device__ __forceinline__ unsigned f2o16(unsigned b) {
  return (b & 0x8000u) ? (~b & 0xFFFFu) : (b | 0x8000u);
}
__device__ __forceinline__ float o2f16v(unsigned key) {
  const unsigned short bb = (key & 0x8000u) ? (unsigned short)(key & 0x7FFFu)
                                            : (unsigned short)(~key & 0xFFFFu);
  return (float)__builtin_bit_cast(_Float16, bb);
}

// --- per-row: exact k-th fp16 threshold + band + bulk a1 write (2 streams) ---
// pass A: 4096-bin hist on key bits 15:4 -> binsel, rem, c_above(bins>=sel+2).
// pass B: one z1 stream: a1 = value for bins > binsel+1 else 0; collect cands
// (bins binsel-1..binsel+1, ~270/row) to LDS. 16-way refine on key bits 3:0
// gives t = exact k-th largest fp16 value. Band = [t-DELTA, t+DELTA] from
// cands. k_select later patches cand sure-ins (v > t+DELTA) and band winners.
__global__ __launch_bounds__(256)
void k_topk16(const unsigned short* __restrict__ z1b, float* __restrict__ thr,
              unsigned* __restrict__ rowlist, unsigned* __restrict__ rowcnt,
              unsigned* __restrict__ c1, unsigned* __restrict__ bucket,
              unsigned* __restrict__ bcnt, unsigned short* __restrict__ a1b,
              float* __restrict__ candv, unsigned short* __restrict__ candi,
              unsigned* __restrict__ candn, int kwant) {
  __shared__ unsigned hist[4096];
  __shared__ float cv[CANDCAP];
  __shared__ unsigned short ci[CANDCAP];
  __shared__ unsigned s_n, s_bin, s_rem, s_wt[4], s_cnt, s_above;
  const int tid = threadIdx.x;
  const int b = blockIdx.x;
  const u16x8* zv = (const u16x8*)(z1b + (long)b * NROWS_W);
  constexpr int NV = NROWS_W / 8;

  // ---- pass A ----
#pragma unroll
  for (int j = 0; j < 16; ++j) hist[tid + j * 256] = 0;
  if (tid == 0) { s_n = 0; s_cnt = 0; s_above = 0; }
  __syncthreads();
  for (int i = tid; i < NV; i += 256) {
    u16x8 v = zv[i];
#pragma unroll
    for (int j = 0; j < 8; ++j) atomicAdd(&hist[f2o16(v[j]) >> 4], 1u);
  }
  __syncthreads();
  unsigned p = 0;
#pragma unroll
  for (int j = 0; j < 16; ++j) p += hist[tid * 16 + j];
  unsigned sfx = p;
  const int lane = tid & 63, w = tid >> 6;
#pragma unroll
  for (int off = 1; off < 64; off <<= 1) {
    unsigned o = __shfl_down(sfx, off);
    sfx += (lane + off < 64) ? o : 0u;
  }
  if (lane == 0) s_wt[w] = sfx;
  __syncthreads();
  unsigned above_waves = 0;
  for (int ww = w + 1; ww < 4; ++ww) above_waves += s_wt[ww];
  const unsigned incl = sfx + above_waves;
  const int cnt = __syncthreads_count(incl >= (unsigned)kwant);
  const int tstar = cnt - 1;
  if (tid == tstar) {
    unsigned cum = incl - p;
    int bsel = tid * 16;
    for (int j = 15; j >= 0; --j) {
      const unsigned h = hist[tid * 16 + j];
      if (cum + h >= (unsigned)kwant) { bsel = tid * 16 + j; break; }
      cum += h;
    }
    s_bin = (unsigned)bsel;
    s_rem = (unsigned)kwant - cum;
  }
  __syncthreads();
  const unsigned binsel = s_bin;
  const unsigned rem = s_rem;

  // c_above: bins >= binsel+2 are all > t+DELTA (bin width >= 16 ulp >= 0.0078
  // at t~1.3 > DELTA)
  {
    unsigned loc = 0;
#pragma unroll
    for (int j = 0; j < 16; ++j) {
      const unsigned bin = tid * 16 + j;
      if (bin >= binsel + 2) loc += hist[bin];
    }
    if (loc) atomicAdd(&s_above, loc);
  }

  // ---- pass B: bulk a1 write + cand collect ----
  const unsigned blo = (binsel > 0) ? binsel - 1 : 0;
  const unsigned bhi = binsel + 1;
  u16x8* av = (u16x8*)(a1b + (long)b * NROWS_W);
  for (int i = tid; i < NV; i += 256) {
    u16x8 v = zv[i];
    u16x8 o;
#pragma unroll
    for (int j = 0; j < 8; ++j) {
      const unsigned bits = v[j];
      const unsigned bin = f2o16(bits) >> 4;
      o[j] = (bin > bhi) ? (unsigned short)bits : (unsigned short)0;
      if (bin >= blo && bin <= bhi) {
        const unsigned jj = atomicAdd(&s_n, 1u);
        if (jj < CANDCAP) {
          cv[jj] = (float)__builtin_bit_cast(_Float16, (unsigned short)bits);
          ci[jj] = (unsigned short)(i * 8 + j);
        }
      }
    }
    av[i] = o;
  }
  __syncthreads();
  const int n = (s_n < CANDCAP) ? (int)s_n : CANDCAP;
  if (tid == 0) candn[b] = (unsigned)n;
  if (tid < 16) hist[tid] = 0;
  __syncthreads();

  // mirror cands to global + refine histogram (low 4 key bits, binsel only)
  for (int i = tid; i < n; i += 256) {
    const float v = cv[i];
    candv[(long)b * CANDCAP + i] = v;
    candi[(long)b * CANDCAP + i] = ci[i];
    const unsigned short bb = __builtin_bit_cast(unsigned short, (_Float16)v);
    const unsigned key = f2o16(bb);
    if ((key >> 4) == binsel) atomicAdd(&hist[key & 15u], 1u);
  }
  __syncthreads();
  if (tid == 0) {
    unsigned cum = 0;
    int d = 15;
    for (; d > 0; --d) {
      if (cum + hist[d] >= rem) break;
      cum += hist[d];
    }
    s_bin = (unsigned)d;
  }
  __syncthreads();
  const float t = o2f16v((binsel << 4) | s_bin);  // exact k-th largest fp16
  if (tid == 0) thr[b] = t;
  const float hi = t + DELTA, lo = t - DELTA;

  // ---- band members from LDS cand list ----
  for (int i = tid; i < n; i += 256) {
    const float v = cv[i];
    if (v >= lo && v <= hi) {
      const unsigned idx = ci[i];
      const unsigned jj = atomicAdd(&s_cnt, 1u);
      if (jj < ROWCAP) {
        rowlist[(long)b * ROWCAP + jj] = idx;
        const unsigned pq = atomicAdd(&bcnt[idx], 1u);
        if (pq < HCAP) bucket[(long)idx * HCAP + pq] = ((unsigned)b << 9) | jj;
      }
    }
  }
  __syncthreads();
  if (tid == 0) {
    rowcnt[b] = (s_cnt < ROWCAP) ? s_cnt : ROWCAP;
    c1[b] = s_above;  // sure-ins OUTSIDE cand bins
  }
}

// -------- h-major exact recompute: fp32 W row in LDS, fp32 x (L3) ----------
__global__ void k_recompute(const float* __restrict__ W, const float* __restrict__ x,
                            const float* __restrict__ b_enc,
                            const unsigned* __restrict__ bucket,
                            const unsigned* __restrict__ bcnt,
                            float* __restrict__ exact) {
  const int h = blockIdx.x;
  unsigned n = bcnt[h];
  if (n > HCAP) n = HCAP;
  if (n == 0) return;
  __shared__ float wrec[DIM];
  const long wb = (long)h * DIM;
  for (int i = threadIdx.x; i < DIM / 4; i += 256)
    ((f32x4*)wrec)[i] = ((const f32x4*)(W + wb))[i];
  __syncthreads();
  const float be = b_enc[h];
  const int w = threadIdx.x >> 6, lane = threadIdx.x & 63;
  for (unsigned e = w; e < n; e += 4) {
    const unsigned ent = bucket[(long)h * HCAP + e];
    const int b = ent >> 9, j = ent & 511;
    const f32x4* xv = (const f32x4*)(x + (long)b * DIM);
    float s = 0.f;
#pragma unroll
    for (int c = 0; c < 16; ++c) {
      const int i4 = c * 64 + lane;
      f32x4 v = xv[i4];
      const float* wr = &wrec[i4 * 4];
#pragma unroll
      for (int q = 0; q < 4; ++q) s += v[q] * wr[q];
    }
#pragma unroll
    for (int m = 32; m; m >>= 1) s += __shfl_xor(s, m);
    if (lane == 0) exact[(long)b * ROWCAP + j] = s + be;
  }
}

// -- per-row: finalize counts, band rank-select, patch cand region of a1 -----
__global__ void k_select(const float* __restrict__ exact, const unsigned* __restrict__ rowlist,
                         const unsigned* __restrict__ rowcnt, const unsigned* __restrict__ c1,
                         const float* __restrict__ thr, const float* __restrict__ candv,
                         const unsigned short* __restrict__ candi,
                         const unsigned* __restrict__ candn,
                         _Float16* __restrict__ a1) {
  const int b = blockIdx.x;
  const int n = (int)rowcnt[b];
  const int nc = (int)candn[b];
  const float t = thr[b];
  const float hi = t + DELTA;
  __shared__ float vals[ROWCAP];
  __shared__ unsigned s_c;
  const int j = threadIdx.x;  // blockDim == ROWCAP == 256
  if (j == 0) s_c = 0;
  vals[j] = (j < n) ? exact[(long)b * ROWCAP + j] : -1e30f;
  __syncthreads();
  // sure-ins inside cand bins
  unsigned loc = 0;
  for (int i = j; i < nc; i += 256) loc += (candv[(long)b * CANDCAP + i] > hi) ? 1u : 0u;
  if (loc) atomicAdd(&s_c, loc);
  __syncthreads();
  const int need = KCNT - (int)c1[b] - (int)s_c;
  // band rank-select -> write winners (value = fp32-exact z1, fp16-rounded)
  if (j < n) {
    const float vj = vals[j];
    int rank = 0;
    for (int i = 0; i < n; ++i) {
      const float vi = vals[i];
      rank += (vi > vj || (vi == vj && i < j)) ? 1 : 0;
    }
    if (rank < need)
      a1[(long)b * NROWS_W + rowlist[(long)b * ROWCAP + j]] = (_Float16)vals[j];
  }
  // patch cand sure-ins (placeholder 0 -> stored fp16 value)
  for (int i = j; i < nc; i += 256) {
    const float v = candv[(long)b * CANDCAP + i];
    if (v > hi) a1[(long)b * NROWS_W + candi[(long)b * CANDCAP + i]] = (_Float16)v;
  }
}

extern "C" void kernel_launch(void* const* d_in, const int* in_sizes, int n_in,
                              void* d_out, int out_size, void* d_ws, size_t ws_size,
                              hipStream_t stream) {
  const float* x     = (const float*)d_in[0];
  const float* W     = (const float*)d_in[1];
  const float* b_enc = (const float*)d_in[2];
  const float* b_dec = (const float*)d_in[3];
  float* out = (float*)d_out;

  const long NW = (long)NROWS_W * DIM;    // 134217728
  const long NX = (long)BATCH * DIM;      // 16777216
  const long NZ = (long)BATCH * NROWS_W;  // 134217728

  char* ws = (char*)d_ws;
  _Float16* Wh = (_Float16*)ws;     // 2*NW (dead after encoder -> reused as a1)
  _Float16* Wt = Wh + NW;           // 2*NW
  _Float16* xh = Wt + NW;           // 2*NX
  _Float16* z1f = xh + NX;          // 2*NZ (fp16 z1)
  float*  thr = (float*)(z1f + NZ); // 4*BATCH
  char*   sc = (char*)(thr + BATCH);
  unsigned* rowcnt  = (unsigned*)sc;                     // 16 KB
  unsigned* c1      = (unsigned*)(sc + 16384);           // 16 KB
  unsigned* bcnt    = (unsigned*)(sc + 32768);           // 128 KB (zeroed in splitw)
  float*    exact   = (float*)(sc + 163840);             // 4 MB
  unsigned* rowlist = (unsigned*)(sc + 4358144);         // 4 MB
  unsigned* bucket  = (unsigned*)(sc + 8552448);         // 8 MB
  unsigned* candn   = (unsigned*)(sc + 16941056);        // 16 KB
  float*    candv   = (float*)(sc + 16957440);           // 8.4 MB
  unsigned short* candi = (unsigned short*)(sc + 25346048);  // 4.2 MB -> end 29.5 MB
  _Float16* a1 = Wh;

  const size_t needed = (size_t)(4 * NW + 2 * NX + 2 * NZ) + 4 * BATCH + 29540352;
  if (ws_size < needed) return;

  k_splitw<<<dim3(DIM / 64, NROWS_W / 64), dim3(64, 8), 0, stream>>>(W, Wh, Wt, (f32x4*)bcnt);
  k_cvtx<<<2048, 256, 0, stream>>>(x, xh, (int)(NX / 4));

  // encoder (approx): z1 = xh @ Wh^T + b_enc -> fp16; supertile 16x32
  k_gemm<BATCH, NROWS_W, DIM, 4, 5, _Float16>
      <<<(BATCH / 128) * (NROWS_W / 128), 256, 0, stream>>>(xh, Wh, b_enc, z1f);

  k_topk16<<<BATCH, 256, 0, stream>>>((const unsigned short*)z1f, thr, rowlist,
                                      rowcnt, c1, bucket, bcnt,
                                      (unsigned short*)a1, candv, candi, candn, KCNT);
  k_recompute<<<NROWS_W, 256, 0, stream>>>(W, x, b_enc, bucket, bcnt, exact);
  k_select<<<BATCH, ROWCAP, 0, stream>>>(exact, rowlist, rowcnt, c1, thr,
                                         candv, candi, candn, a1);

  // decoder: out = a1 @ W + b_dec (B^T = Wt); supertile 16x32
  k_gemm<BATCH, DIM, NROWS_W, 4, 5, float>
      <<<(BATCH / 128) * (DIM / 128), 256, 0, stream>>>(a1, Wt, b_dec, out);
}

// Round 13
// 3056.506 us; speedup vs baseline: 1.1231x; 1.0336x over previous
//
#include <hip/hip_runtime.h>
#include <hip/hip_bf16.h>
#include <hip/hip_fp16.h>
#include <stdint.h>

// Sparse autoencoder: z1 = x@W^T + b_enc ; top-k(3276) mask ; z2 = a1@W + b_dec
// Encoder = single fp16 MFMA GEMM writing fp16 z1; exact top-k selection via
// fp32 band recompute near the exact k-th fp16 threshold (h-major, W streamed
// once, fp32 x L3-resident). GEMMs: proven 128^2 m97-structure + T2 swizzle +
// supertile remap on RAW blockIdx. Decoder supertile 16x8: K=32768 strips are
// 8.4 MB -> 16x8 = 202 MB working set fits L3 (16x32 was 403 MB -> 2.9 GB
// FETCH thrash, measured R10-R12).

#define DIM      4096
#define BATCH    4096
#define NROWS_W  32768
#define KCNT     3276
#define DELTA    0.003f
#define ROWCAP   256
#define HCAP     64
#define CANDCAP  512

typedef _Float16 f16x8 __attribute__((ext_vector_type(8)));
typedef _Float16 f16x4 __attribute__((ext_vector_type(4)));
typedef float    f32x4 __attribute__((ext_vector_type(4)));
typedef unsigned short u16x8 __attribute__((ext_vector_type(8)));

__device__ __forceinline__ void gload_lds16(const void* g, void* l) {
  __builtin_amdgcn_global_load_lds(
      (const __attribute__((address_space(1))) void*)g,
      (__attribute__((address_space(3))) void*)l, 16, 0, 0);
}

// ---------------- x: fp32 -> fp16 (encoder A operand) ----------------
__global__ void k_cvtx(const float* __restrict__ s, _Float16* __restrict__ hi, int n4) {
  int i = blockIdx.x * 256 + threadIdx.x;
  const int stride = gridDim.x * 256;
  for (; i < n4; i += stride) {
    f32x4 v = ((const f32x4*)s)[i];
    f16x4 h;
#pragma unroll
    for (int j = 0; j < 4; ++j) h[j] = (_Float16)v[j];
    ((f16x4*)hi)[i] = h;
  }
}

// --- fused W convert+transpose: W fp32 -> Wh fp16 [H,D] + Wt fp16 [D,H] ------
// Also zeroes bcnt (blockIdx.y==0 blocks) to save a launch.
__global__ void k_splitw(const float* __restrict__ W, _Float16* __restrict__ Wh,
                         _Float16* __restrict__ Wt, f32x4* __restrict__ bcntv) {
  __shared__ _Float16 t[64][65];
  const int c0 = blockIdx.x * 64, r0 = blockIdx.y * 64;
  const int tx = threadIdx.x, ty = threadIdx.y;  // (64, 8)
  if (blockIdx.y == 0) {
    const int idx = blockIdx.x * 512 + ty * 64 + tx;
    if (idx < 8192) {  // 128 KB bcnt
      f32x4 z = {0.f, 0.f, 0.f, 0.f};
      bcntv[idx] = z;
    }
  }
  for (int rr = ty; rr < 64; rr += 8) {
    const float w = W[(long)(r0 + rr) * DIM + c0 + tx];
    const _Float16 h = (_Float16)w;
    Wh[(long)(r0 + rr) * DIM + c0 + tx] = h;
    t[rr][tx] = h;
  }
  __syncthreads();
  for (int cc = ty; cc < 64; cc += 8)
    Wt[(long)(c0 + cc) * NROWS_W + r0 + tx] = t[tx][cc];
}

// ---------------- GEMM: C[M,N] = A[M,K] * B^T[N,K] + bias (proven R10) -------
// T2 XOR-swizzled LDS; (2^SML x 2^SNL) supertile remap on raw blockIdx.
template <int MT, int NTOT, int KT, int SML, int SNL, typename OutT>
__global__ __launch_bounds__(256, 2)
void k_gemm(const _Float16* __restrict__ A, const _Float16* __restrict__ B,
            const float* __restrict__ bias, OutT* __restrict__ C) {
  constexpr int BM = 128, BN = 128, BK = 64;
  __shared__ __align__(16) _Float16 sA[BM * BK];
  __shared__ __align__(16) _Float16 sB[BN * BK];

  const int tid = threadIdx.x;
  constexpr int nbn = NTOT / BN;
  constexpr int nstn = nbn >> SNL;
  constexpr int stsz = 1 << (SML + SNL);

  const int g = blockIdx.x >> (SML + SNL), r = blockIdx.x & (stsz - 1);
  const int bm = ((g / nstn) << SML) + (r >> SNL);
  const int bn = ((g % nstn) << SNL) + (r & ((1 << SNL) - 1));

  const int m0 = bm * BM, n0 = bn * BN;
  const int lane = tid & 63, wid = tid >> 6;
  const int wm = wid >> 1, wn = wid & 1;
  const int lr = lane & 15, lk = lane >> 4;
  const int swz = (lr & 7) << 4;

  f32x4 acc[4][4] = {};

  for (int k0 = 0; k0 < KT; k0 += BK) {
#pragma unroll
    for (int rr = 0; rr < 4; ++rr) {
      const int o = (rr * 256 + tid) * 16;
      const int row = o >> 7;
      const int colb = (o & 127) ^ ((row & 7) << 4);
      const long gA = ((long)(m0 + row) * KT + k0) * 2 + colb;
      const long gB = ((long)(n0 + row) * KT + k0) * 2 + colb;
      gload_lds16((const char*)A + gA, (char*)sA + o);
      gload_lds16((const char*)B + gB, (char*)sB + o);
    }
    __syncthreads();

#pragma unroll
    for (int kk = 0; kk < 2; ++kk) {
      f16x8 va[4], vb[4];
      const int kbase = (kk * 64 + lk * 16) ^ swz;
#pragma unroll
      for (int m = 0; m < 4; ++m) {
        const int row = wm * 64 + m * 16 + lr;
        va[m] = *(const f16x8*)((const char*)sA + row * 128 + kbase);
      }
#pragma unroll
      for (int n = 0; n < 4; ++n) {
        const int row = wn * 64 + n * 16 + lr;
        vb[n] = *(const f16x8*)((const char*)sB + row * 128 + kbase);
      }
#pragma unroll
      for (int m = 0; m < 4; ++m)
#pragma unroll
        for (int n = 0; n < 4; ++n)
          acc[m][n] = __builtin_amdgcn_mfma_f32_16x16x32_f16(va[m], vb[n], acc[m][n], 0, 0, 0);
    }
    __syncthreads();
  }

  // C/D layout: col = lane&15, row = (lane>>4)*4 + reg
#pragma unroll
  for (int n = 0; n < 4; ++n) {
    const int col = n0 + wn * 64 + n * 16 + lr;
    const float bv = bias[col];
#pragma unroll
    for (int m = 0; m < 4; ++m) {
      const int r0r = m0 + wm * 64 + m * 16 + lk * 4;
#pragma unroll
      for (int j = 0; j < 4; ++j)
        C[(long)(r0r + j) * NTOT + col] = (OutT)(acc[m][n][j] + bv);
    }
  }
}

// ------------- fp16 bits <-> order-preserving 16-bit key ----------------
__device__ __forceinline__ unsigned f2o16(unsigned b) {
  return (b & 0x8000u) ? (~b & 0xFFFFu) : (b | 0x8000u);
}
__device__ __forceinline__ float o2f16v(unsigned key) {
  const unsigned short bb = (key & 0x8000u) ? (unsigned short)(key & 0x7FFFu)
                                            : (unsigned short)(~key & 0xFFFFu);
  return (float)__builtin_bit_cast(_Float16, bb);
}

// --- per-row: exact k-th fp16 threshold + band + bulk a1 write (2 streams) ---
__global__ __launch_bounds__(256)
void k_topk16(const unsigned short* __restrict__ z1b, float* __restrict__ thr,
              unsigned* __restrict__ rowlist, unsigned* __restrict__ rowcnt,
              unsigned* __restrict__ c1, unsigned* __restrict__ bucket,
              unsigned* __restrict__ bcnt, unsigned short* __restrict__ a1b,
              float* __restrict__ candv, unsigned short* __restrict__ candi,
              unsigned* __restrict__ candn, int kwant) {
  __shared__ unsigned hist[4096];
  __shared__ float cv[CANDCAP];
  __shared__ unsigned short ci[CANDCAP];
  __shared__ unsigned s_n, s_bin, s_rem, s_wt[4], s_cnt, s_above;
  const int tid = threadIdx.x;
  const int b = blockIdx.x;
  const u16x8* zv = (const u16x8*)(z1b + (long)b * NROWS_W);
  constexpr int NV = NROWS_W / 8;

  // ---- pass A: 4096-bin histogram on key bits 15:4 ----
#pragma unroll
  for (int j = 0; j < 16; ++j) hist[tid + j * 256] = 0;
  if (tid == 0) { s_n = 0; s_cnt = 0; s_above = 0; }
  __syncthreads();
  for (int i = tid; i < NV; i += 256) {
    u16x8 v = zv[i];
#pragma unroll
    for (int j = 0; j < 8; ++j) atomicAdd(&hist[f2o16(v[j]) >> 4], 1u);
  }
  __syncthreads();
  unsigned p = 0;
#pragma unroll
  for (int j = 0; j < 16; ++j) p += hist[tid * 16 + j];
  unsigned sfx = p;
  const int lane = tid & 63, w = tid >> 6;
#pragma unroll
  for (int off = 1; off < 64; off <<= 1) {
    unsigned o = __shfl_down(sfx, off);
    sfx += (lane + off < 64) ? o : 0u;
  }
  if (lane == 0) s_wt[w] = sfx;
  __syncthreads();
  unsigned above_waves = 0;
  for (int ww = w + 1; ww < 4; ++ww) above_waves += s_wt[ww];
  const unsigned incl = sfx + above_waves;
  const int cnt = __syncthreads_count(incl >= (unsigned)kwant);
  const int tstar = cnt - 1;
  if (tid == tstar) {
    unsigned cum = incl - p;
    int bsel = tid * 16;
    for (int j = 15; j >= 0; --j) {
      const unsigned h = hist[tid * 16 + j];
      if (cum + h >= (unsigned)kwant) { bsel = tid * 16 + j; break; }
      cum += h;
    }
    s_bin = (unsigned)bsel;
    s_rem = (unsigned)kwant - cum;
  }
  __syncthreads();
  const unsigned binsel = s_bin;
  const unsigned rem = s_rem;

  // c_above: bins >= binsel+2 are all > t+DELTA (bin width = 16 ulp >= 0.0078
  // at t~1.3 > DELTA)
  {
    unsigned loc = 0;
#pragma unroll
    for (int j = 0; j < 16; ++j) {
      const unsigned bin = tid * 16 + j;
      if (bin >= binsel + 2) loc += hist[bin];
    }
    if (loc) atomicAdd(&s_above, loc);
  }

  // ---- pass B: bulk a1 write + cand collect (bins binsel-1..binsel+1) ----
  const unsigned blo = (binsel > 0) ? binsel - 1 : 0;
  const unsigned bhi = binsel + 1;
  u16x8* av = (u16x8*)(a1b + (long)b * NROWS_W);
  for (int i = tid; i < NV; i += 256) {
    u16x8 v = zv[i];
    u16x8 o;
#pragma unroll
    for (int j = 0; j < 8; ++j) {
      const unsigned bits = v[j];
      const unsigned bin = f2o16(bits) >> 4;
      o[j] = (bin > bhi) ? (unsigned short)bits : (unsigned short)0;
      if (bin >= blo && bin <= bhi) {
        const unsigned jj = atomicAdd(&s_n, 1u);
        if (jj < CANDCAP) {
          cv[jj] = (float)__builtin_bit_cast(_Float16, (unsigned short)bits);
          ci[jj] = (unsigned short)(i * 8 + j);
        }
      }
    }
    av[i] = o;
  }
  __syncthreads();
  const int n = (s_n < CANDCAP) ? (int)s_n : CANDCAP;
  if (tid == 0) candn[b] = (unsigned)n;
  if (tid < 16) hist[tid] = 0;
  __syncthreads();

  // mirror cands to global + refine histogram (low 4 key bits, binsel only)
  for (int i = tid; i < n; i += 256) {
    const float v = cv[i];
    candv[(long)b * CANDCAP + i] = v;
    candi[(long)b * CANDCAP + i] = ci[i];
    const unsigned short bb = __builtin_bit_cast(unsigned short, (_Float16)v);
    const unsigned key = f2o16(bb);
    if ((key >> 4) == binsel) atomicAdd(&hist[key & 15u], 1u);
  }
  __syncthreads();
  if (tid == 0) {
    unsigned cum = 0;
    int d = 15;
    for (; d > 0; --d) {
      if (cum + hist[d] >= rem) break;
      cum += hist[d];
    }
    s_bin = (unsigned)d;
  }
  __syncthreads();
  const float t = o2f16v((binsel << 4) | s_bin);  // exact k-th largest fp16
  if (tid == 0) thr[b] = t;
  const float hi = t + DELTA, lo = t - DELTA;

  // ---- band members from LDS cand list ----
  for (int i = tid; i < n; i += 256) {
    const float v = cv[i];
    if (v >= lo && v <= hi) {
      const unsigned idx = ci[i];
      const unsigned jj = atomicAdd(&s_cnt, 1u);
      if (jj < ROWCAP) {
        rowlist[(long)b * ROWCAP + jj] = idx;
        const unsigned pq = atomicAdd(&bcnt[idx], 1u);
        if (pq < HCAP) bucket[(long)idx * HCAP + pq] = ((unsigned)b << 9) | jj;
      }
    }
  }
  __syncthreads();
  if (tid == 0) {
    rowcnt[b] = (s_cnt < ROWCAP) ? s_cnt : ROWCAP;
    c1[b] = s_above;  // sure-ins OUTSIDE cand bins
  }
}

// -------- h-major exact recompute: fp32 W row in LDS, fp32 x (L3) ----------
__global__ void k_recompute(const float* __restrict__ W, const float* __restrict__ x,
                            const float* __restrict__ b_enc,
                            const unsigned* __restrict__ bucket,
                            const unsigned* __restrict__ bcnt,
                            float* __restrict__ exact) {
  const int h = blockIdx.x;
  unsigned n = bcnt[h];
  if (n > HCAP) n = HCAP;
  if (n == 0) return;
  __shared__ float wrec[DIM];
  const long wb = (long)h * DIM;
  for (int i = threadIdx.x; i < DIM / 4; i += 256)
    ((f32x4*)wrec)[i] = ((const f32x4*)(W + wb))[i];
  __syncthreads();
  const float be = b_enc[h];
  const int w = threadIdx.x >> 6, lane = threadIdx.x & 63;
  for (unsigned e = w; e < n; e += 4) {
    const unsigned ent = bucket[(long)h * HCAP + e];
    const int b = ent >> 9, j = ent & 511;
    const f32x4* xv = (const f32x4*)(x + (long)b * DIM);
    float s = 0.f;
#pragma unroll
    for (int c = 0; c < 16; ++c) {
      const int i4 = c * 64 + lane;
      f32x4 v = xv[i4];
      const float* wr = &wrec[i4 * 4];
#pragma unroll
      for (int q = 0; q < 4; ++q) s += v[q] * wr[q];
    }
#pragma unroll
    for (int m = 32; m; m >>= 1) s += __shfl_xor(s, m);
    if (lane == 0) exact[(long)b * ROWCAP + j] = s + be;
  }
}

// -- per-row: finalize counts, band rank-select, patch cand region of a1 -----
__global__ void k_select(const float* __restrict__ exact, const unsigned* __restrict__ rowlist,
                         const unsigned* __restrict__ rowcnt, const unsigned* __restrict__ c1,
                         const float* __restrict__ thr, const float* __restrict__ candv,
                         const unsigned short* __restrict__ candi,
                         const unsigned* __restrict__ candn,
                         _Float16* __restrict__ a1) {
  const int b = blockIdx.x;
  const int n = (int)rowcnt[b];
  const int nc = (int)candn[b];
  const float t = thr[b];
  const float hi = t + DELTA;
  __shared__ float vals[ROWCAP];
  __shared__ unsigned s_c;
  const int j = threadIdx.x;  // blockDim == ROWCAP == 256
  if (j == 0) s_c = 0;
  vals[j] = (j < n) ? exact[(long)b * ROWCAP + j] : -1e30f;
  __syncthreads();
  // sure-ins inside cand bins
  unsigned loc = 0;
  for (int i = j; i < nc; i += 256) loc += (candv[(long)b * CANDCAP + i] > hi) ? 1u : 0u;
  if (loc) atomicAdd(&s_c, loc);
  __syncthreads();
  const int need = KCNT - (int)c1[b] - (int)s_c;
  // band rank-select -> write winners
  if (j < n) {
    const float vj = vals[j];
    int rank = 0;
    for (int i = 0; i < n; ++i) {
      const float vi = vals[i];
      rank += (vi > vj || (vi == vj && i < j)) ? 1 : 0;
    }
    if (rank < need)
      a1[(long)b * NROWS_W + rowlist[(long)b * ROWCAP + j]] = (_Float16)vals[j];
  }
  // patch cand sure-ins (placeholder 0 -> stored fp16 value)
  for (int i = j; i < nc; i += 256) {
    const float v = candv[(long)b * CANDCAP + i];
    if (v > hi) a1[(long)b * NROWS_W + candi[(long)b * CANDCAP + i]] = (_Float16)v;
  }
}

extern "C" void kernel_launch(void* const* d_in, const int* in_sizes, int n_in,
                              void* d_out, int out_size, void* d_ws, size_t ws_size,
                              hipStream_t stream) {
  const float* x     = (const float*)d_in[0];
  const float* W     = (const float*)d_in[1];
  const float* b_enc = (const float*)d_in[2];
  const float* b_dec = (const float*)d_in[3];
  float* out = (float*)d_out;

  const long NW = (long)NROWS_W * DIM;    // 134217728
  const long NX = (long)BATCH * DIM;      // 16777216
  const long NZ = (long)BATCH * NROWS_W;  // 134217728

  char* ws = (char*)d_ws;
  _Float16* Wh = (_Float16*)ws;     // 2*NW (dead after encoder -> reused as a1)
  _Float16* Wt = Wh + NW;           // 2*NW
  _Float16* xh = Wt + NW;           // 2*NX
  _Float16* z1f = xh + NX;          // 2*NZ (fp16 z1)
  float*  thr = (float*)(z1f + NZ); // 4*BATCH
  char*   sc = (char*)(thr + BATCH);
  unsigned* rowcnt  = (unsigned*)sc;                     // 16 KB
  unsigned* c1      = (unsigned*)(sc + 16384);           // 16 KB
  unsigned* bcnt    = (unsigned*)(sc + 32768);           // 128 KB (zeroed in splitw)
  float*    exact   = (float*)(sc + 163840);             // 4 MB
  unsigned* rowlist = (unsigned*)(sc + 4358144);         // 4 MB
  unsigned* bucket  = (unsigned*)(sc + 8552448);         // 8 MB
  unsigned* candn   = (unsigned*)(sc + 16941056);        // 16 KB
  float*    candv   = (float*)(sc + 16957440);           // 8.4 MB
  unsigned short* candi = (unsigned short*)(sc + 25346048);  // 4.2 MB -> end 29.5 MB
  _Float16* a1 = Wh;

  const size_t needed = (size_t)(4 * NW + 2 * NX + 2 * NZ) + 4 * BATCH + 29540352;
  if (ws_size < needed) return;

  k_splitw<<<dim3(DIM / 64, NROWS_W / 64), dim3(64, 8), 0, stream>>>(W, Wh, Wt, (f32x4*)bcnt);
  k_cvtx<<<2048, 256, 0, stream>>>(x, xh, (int)(NX / 4));

  // encoder (approx): z1 = xh @ Wh^T + b_enc -> fp16; supertile 16x32
  k_gemm<BATCH, NROWS_W, DIM, 4, 5, _Float16>
      <<<(BATCH / 128) * (NROWS_W / 128), 256, 0, stream>>>(xh, Wh, b_enc, z1f);

  k_topk16<<<BATCH, 256, 0, stream>>>((const unsigned short*)z1f, thr, rowlist,
                                      rowcnt, c1, bucket, bcnt,
                                      (unsigned short*)a1, candv, candi, candn, KCNT);
  k_recompute<<<NROWS_W, 256, 0, stream>>>(W, x, b_enc, bucket, bcnt, exact);
  k_select<<<BATCH, ROWCAP, 0, stream>>>(exact, rowlist, rowcnt, c1, thr,
                                         candv, candi, candn, a1);

  // decoder: out = a1 @ W + b_dec (B^T = Wt); supertile 16x8 -> 202 MB ws < L3
  k_gemm<BATCH, DIM, NROWS_W, 4, 3, float>
      <<<(BATCH / 128) * (DIM / 128), 256, 0, stream>>>(a1, Wt, b_dec, out);
}

// Round 14
// 2984.884 us; speedup vs baseline: 1.1500x; 1.0240x over previous
//
#include <hip/hip_runtime.h>
#include <hip/hip_bf16.h>
#include <hip/hip_fp16.h>
#include <stdint.h>

// Sparse autoencoder: z1 = x@W^T + b_enc ; top-k(3276) mask ; z2 = a1@W + b_dec
// Encoder = single fp16 MFMA GEMM writing fp16 z1; exact top-k selection via
// fp32 band recompute near the exact k-th fp16 threshold (h-major, W streamed
// once, fp32 x L3-resident). GEMMs: proven 128^2 m97-structure + T2 swizzle +
// 16x32 supertile remap on RAW blockIdx for BOTH GEMMs (measured best across
// R10-R13: decoder 16x8 -> 3.5 GB FETCH / +65 us; XCD chunking -> +14%).

#define DIM      4096
#define BATCH    4096
#define NROWS_W  32768
#define KCNT     3276
#define DELTA    0.003f
#define ROWCAP   256
#define HCAP     64
#define CANDCAP  512

typedef _Float16 f16x8 __attribute__((ext_vector_type(8)));
typedef _Float16 f16x4 __attribute__((ext_vector_type(4)));
typedef float    f32x4 __attribute__((ext_vector_type(4)));
typedef unsigned short u16x8 __attribute__((ext_vector_type(8)));

__device__ __forceinline__ void gload_lds16(const void* g, void* l) {
  __builtin_amdgcn_global_load_lds(
      (const __attribute__((address_space(1))) void*)g,
      (__attribute__((address_space(3))) void*)l, 16, 0, 0);
}

// ---------------- x: fp32 -> fp16 (encoder A operand) ----------------
__global__ void k_cvtx(const float* __restrict__ s, _Float16* __restrict__ hi, int n4) {
  int i = blockIdx.x * 256 + threadIdx.x;
  const int stride = gridDim.x * 256;
  for (; i < n4; i += stride) {
    f32x4 v = ((const f32x4*)s)[i];
    f16x4 h;
#pragma unroll
    for (int j = 0; j < 4; ++j) h[j] = (_Float16)v[j];
    ((f16x4*)hi)[i] = h;
  }
}

// --- fused W convert+transpose: W fp32 -> Wh fp16 [H,D] + Wt fp16 [D,H] ------
// Also zeroes bcnt (blockIdx.y==0 blocks) to save a launch.
__global__ void k_splitw(const float* __restrict__ W, _Float16* __restrict__ Wh,
                         _Float16* __restrict__ Wt, f32x4* __restrict__ bcntv) {
  __shared__ _Float16 t[64][65];
  const int c0 = blockIdx.x * 64, r0 = blockIdx.y * 64;
  const int tx = threadIdx.x, ty = threadIdx.y;  // (64, 8)
  if (blockIdx.y == 0) {
    const int idx = blockIdx.x * 512 + ty * 64 + tx;
    if (idx < 8192) {  // 128 KB bcnt
      f32x4 z = {0.f, 0.f, 0.f, 0.f};
      bcntv[idx] = z;
    }
  }
  for (int rr = ty; rr < 64; rr += 8) {
    const float w = W[(long)(r0 + rr) * DIM + c0 + tx];
    const _Float16 h = (_Float16)w;
    Wh[(long)(r0 + rr) * DIM + c0 + tx] = h;
    t[rr][tx] = h;
  }
  __syncthreads();
  for (int cc = ty; cc < 64; cc += 8)
    Wt[(long)(c0 + cc) * NROWS_W + r0 + tx] = t[tx][cc];
}

// ---------------- GEMM: C[M,N] = A[M,K] * B^T[N,K] + bias (proven R10) -------
// T2 XOR-swizzled LDS; (2^SML x 2^SNL) supertile remap on raw blockIdx.
template <int MT, int NTOT, int KT, int SML, int SNL, typename OutT>
__global__ __launch_bounds__(256, 2)
void k_gemm(const _Float16* __restrict__ A, const _Float16* __restrict__ B,
            const float* __restrict__ bias, OutT* __restrict__ C) {
  constexpr int BM = 128, BN = 128, BK = 64;
  __shared__ __align__(16) _Float16 sA[BM * BK];
  __shared__ __align__(16) _Float16 sB[BN * BK];

  const int tid = threadIdx.x;
  constexpr int nbn = NTOT / BN;
  constexpr int nstn = nbn >> SNL;
  constexpr int stsz = 1 << (SML + SNL);

  const int g = blockIdx.x >> (SML + SNL), r = blockIdx.x & (stsz - 1);
  const int bm = ((g / nstn) << SML) + (r >> SNL);
  const int bn = ((g % nstn) << SNL) + (r & ((1 << SNL) - 1));

  const int m0 = bm * BM, n0 = bn * BN;
  const int lane = tid & 63, wid = tid >> 6;
  const int wm = wid >> 1, wn = wid & 1;
  const int lr = lane & 15, lk = lane >> 4;
  const int swz = (lr & 7) << 4;

  f32x4 acc[4][4] = {};

  for (int k0 = 0; k0 < KT; k0 += BK) {
#pragma unroll
    for (int rr = 0; rr < 4; ++rr) {
      const int o = (rr * 256 + tid) * 16;
      const int row = o >> 7;
      const int colb = (o & 127) ^ ((row & 7) << 4);
      const long gA = ((long)(m0 + row) * KT + k0) * 2 + colb;
      const long gB = ((long)(n0 + row) * KT + k0) * 2 + colb;
      gload_lds16((const char*)A + gA, (char*)sA + o);
      gload_lds16((const char*)B + gB, (char*)sB + o);
    }
    __syncthreads();

#pragma unroll
    for (int kk = 0; kk < 2; ++kk) {
      f16x8 va[4], vb[4];
      const int kbase = (kk * 64 + lk * 16) ^ swz;
#pragma unroll
      for (int m = 0; m < 4; ++m) {
        const int row = wm * 64 + m * 16 + lr;
        va[m] = *(const f16x8*)((const char*)sA + row * 128 + kbase);
      }
#pragma unroll
      for (int n = 0; n < 4; ++n) {
        const int row = wn * 64 + n * 16 + lr;
        vb[n] = *(const f16x8*)((const char*)sB + row * 128 + kbase);
      }
#pragma unroll
      for (int m = 0; m < 4; ++m)
#pragma unroll
        for (int n = 0; n < 4; ++n)
          acc[m][n] = __builtin_amdgcn_mfma_f32_16x16x32_f16(va[m], vb[n], acc[m][n], 0, 0, 0);
    }
    __syncthreads();
  }

  // C/D layout: col = lane&15, row = (lane>>4)*4 + reg
#pragma unroll
  for (int n = 0; n < 4; ++n) {
    const int col = n0 + wn * 64 + n * 16 + lr;
    const float bv = bias[col];
#pragma unroll
    for (int m = 0; m < 4; ++m) {
      const int r0r = m0 + wm * 64 + m * 16 + lk * 4;
#pragma unroll
      for (int j = 0; j < 4; ++j)
        C[(long)(r0r + j) * NTOT + col] = (OutT)(acc[m][n][j] + bv);
    }
  }
}

// ------------- fp16 bits <-> order-preserving 16-bit key ----------------
__device__ __forceinline__ unsigned f2o16(unsigned b) {
  return (b & 0x8000u) ? (~b & 0xFFFFu) : (b | 0x8000u);
}
__device__ __forceinline__ float o2f16v(unsigned key) {
  const unsigned short bb = (key & 0x8000u) ? (unsigned short)(key & 0x7FFFu)
                                            : (unsigned short)(~key & 0xFFFFu);
  return (float)__builtin_bit_cast(_Float16, bb);
}

// --- per-row: exact k-th fp16 threshold + band + bulk a1 write (2 streams) ---
__global__ __launch_bounds__(256)
void k_topk16(const unsigned short* __restrict__ z1b, float* __restrict__ thr,
              unsigned* __restrict__ rowlist, unsigned* __restrict__ rowcnt,
              unsigned* __restrict__ c1, unsigned* __restrict__ bucket,
              unsigned* __restrict__ bcnt, unsigned short* __restrict__ a1b,
              float* __restrict__ candv, unsigned short* __restrict__ candi,
              unsigned* __restrict__ candn, int kwant) {
  __shared__ unsigned hist[4096];
  __shared__ float cv[CANDCAP];
  __shared__ unsigned short ci[CANDCAP];
  __shared__ unsigned s_n, s_bin, s_rem, s_wt[4], s_cnt, s_above;
  const int tid = threadIdx.x;
  const int b = blockIdx.x;
  const u16x8* zv = (const u16x8*)(z1b + (long)b * NROWS_W);
  constexpr int NV = NROWS_W / 8;

  // ---- pass A: 4096-bin histogram on key bits 15:4 ----
#pragma unroll
  for (int j = 0; j < 16; ++j) hist[tid + j * 256] = 0;
  if (tid == 0) { s_n = 0; s_cnt = 0; s_above = 0; }
  __syncthreads();
  for (int i = tid; i < NV; i += 256) {
    u16x8 v = zv[i];
#pragma unroll
    for (int j = 0; j < 8; ++j) atomicAdd(&hist[f2o16(v[j]) >> 4], 1u);
  }
  __syncthreads();
  unsigned p = 0;
#pragma unroll
  for (int j = 0; j < 16; ++j) p += hist[tid * 16 + j];
  unsigned sfx = p;
  const int lane = tid & 63, w = tid >> 6;
#pragma unroll
  for (int off = 1; off < 64; off <<= 1) {
    unsigned o = __shfl_down(sfx, off);
    sfx += (lane + off < 64) ? o : 0u;
  }
  if (lane == 0) s_wt[w] = sfx;
  __syncthreads();
  unsigned above_waves = 0;
  for (int ww = w + 1; ww < 4; ++ww) above_waves += s_wt[ww];
  const unsigned incl = sfx + above_waves;
  const int cnt = __syncthreads_count(incl >= (unsigned)kwant);
  const int tstar = cnt - 1;
  if (tid == tstar) {
    unsigned cum = incl - p;
    int bsel = tid * 16;
    for (int j = 15; j >= 0; --j) {
      const unsigned h = hist[tid * 16 + j];
      if (cum + h >= (unsigned)kwant) { bsel = tid * 16 + j; break; }
      cum += h;
    }
    s_bin = (unsigned)bsel;
    s_rem = (unsigned)kwant - cum;
  }
  __syncthreads();
  const unsigned binsel = s_bin;
  const unsigned rem = s_rem;

  // c_above: bins >= binsel+2 are all > t+DELTA (bin width = 16 ulp >= 0.0078
  // at t~1.3 > DELTA)
  {
    unsigned loc = 0;
#pragma unroll
    for (int j = 0; j < 16; ++j) {
      const unsigned bin = tid * 16 + j;
      if (bin >= binsel + 2) loc += hist[bin];
    }
    if (loc) atomicAdd(&s_above, loc);
  }

  // ---- pass B: bulk a1 write + cand collect (bins binsel-1..binsel+1) ----
  const unsigned blo = (binsel > 0) ? binsel - 1 : 0;
  const unsigned bhi = binsel + 1;
  u16x8* av = (u16x8*)(a1b + (long)b * NROWS_W);
  for (int i = tid; i < NV; i += 256) {
    u16x8 v = zv[i];
    u16x8 o;
#pragma unroll
    for (int j = 0; j < 8; ++j) {
      const unsigned bits = v[j];
      const unsigned bin = f2o16(bits) >> 4;
      o[j] = (bin > bhi) ? (unsigned short)bits : (unsigned short)0;
      if (bin >= blo && bin <= bhi) {
        const unsigned jj = atomicAdd(&s_n, 1u);
        if (jj < CANDCAP) {
          cv[jj] = (float)__builtin_bit_cast(_Float16, (unsigned short)bits);
          ci[jj] = (unsigned short)(i * 8 + j);
        }
      }
    }
    av[i] = o;
  }
  __syncthreads();
  const int n = (s_n < CANDCAP) ? (int)s_n : CANDCAP;
  if (tid == 0) candn[b] = (unsigned)n;
  if (tid < 16) hist[tid] = 0;
  __syncthreads();

  // mirror cands to global + refine histogram (low 4 key bits, binsel only)
  for (int i = tid; i < n; i += 256) {
    const float v = cv[i];
    candv[(long)b * CANDCAP + i] = v;
    candi[(long)b * CANDCAP + i] = ci[i];
    const unsigned short bb = __builtin_bit_cast(unsigned short, (_Float16)v);
    const unsigned key = f2o16(bb);
    if ((key >> 4) == binsel) atomicAdd(&hist[key & 15u], 1u);
  }
  __syncthreads();
  if (tid == 0) {
    unsigned cum = 0;
    int d = 15;
    for (; d > 0; --d) {
      if (cum + hist[d] >= rem) break;
      cum += hist[d];
    }
    s_bin = (unsigned)d;
  }
  __syncthreads();
  const float t = o2f16v((binsel << 4) | s_bin);  // exact k-th largest fp16
  if (tid == 0) thr[b] = t;
  const float hi = t + DELTA, lo = t - DELTA;

  // ---- band members from LDS cand list ----
  for (int i = tid; i < n; i += 256) {
    const float v = cv[i];
    if (v >= lo && v <= hi) {
      const unsigned idx = ci[i];
      const unsigned jj = atomicAdd(&s_cnt, 1u);
      if (jj < ROWCAP) {
        rowlist[(long)b * ROWCAP + jj] = idx;
        const unsigned pq = atomicAdd(&bcnt[idx], 1u);
        if (pq < HCAP) bucket[(long)idx * HCAP + pq] = ((unsigned)b << 9) | jj;
      }
    }
  }
  __syncthreads();
  if (tid == 0) {
    rowcnt[b] = (s_cnt < ROWCAP) ? s_cnt : ROWCAP;
    c1[b] = s_above;  // sure-ins OUTSIDE cand bins
  }
}

// -------- h-major exact recompute: fp32 W row in LDS, fp32 x (L3) ----------
__global__ void k_recompute(const float* __restrict__ W, const float* __restrict__ x,
                            const float* __restrict__ b_enc,
                            const unsigned* __restrict__ bucket,
                            const unsigned* __restrict__ bcnt,
                            float* __restrict__ exact) {
  const int h = blockIdx.x;
  unsigned n = bcnt[h];
  if (n > HCAP) n = HCAP;
  if (n == 0) return;
  __shared__ float wrec[DIM];
  const long wb = (long)h * DIM;
  for (int i = threadIdx.x; i < DIM / 4; i += 256)
    ((f32x4*)wrec)[i] = ((const f32x4*)(W + wb))[i];
  __syncthreads();
  const float be = b_enc[h];
  const int w = threadIdx.x >> 6, lane = threadIdx.x & 63;
  for (unsigned e = w; e < n; e += 4) {
    const unsigned ent = bucket[(long)h * HCAP + e];
    const int b = ent >> 9, j = ent & 511;
    const f32x4* xv = (const f32x4*)(x + (long)b * DIM);
    float s = 0.f;
#pragma unroll
    for (int c = 0; c < 16; ++c) {
      const int i4 = c * 64 + lane;
      f32x4 v = xv[i4];
      const float* wr = &wrec[i4 * 4];
#pragma unroll
      for (int q = 0; q < 4; ++q) s += v[q] * wr[q];
    }
#pragma unroll
    for (int m = 32; m; m >>= 1) s += __shfl_xor(s, m);
    if (lane == 0) exact[(long)b * ROWCAP + j] = s + be;
  }
}

// -- per-row: finalize counts, band rank-select, patch cand region of a1 -----
__global__ void k_select(const float* __restrict__ exact, const unsigned* __restrict__ rowlist,
                         const unsigned* __restrict__ rowcnt, const unsigned* __restrict__ c1,
                         const float* __restrict__ thr, const float* __restrict__ candv,
                         const unsigned short* __restrict__ candi,
                         const unsigned* __restrict__ candn,
                         _Float16* __restrict__ a1) {
  const int b = blockIdx.x;
  const int n = (int)rowcnt[b];
  const int nc = (int)candn[b];
  const float t = thr[b];
  const float hi = t + DELTA;
  __shared__ float vals[ROWCAP];
  __shared__ unsigned s_c;
  const int j = threadIdx.x;  // blockDim == ROWCAP == 256
  if (j == 0) s_c = 0;
  vals[j] = (j < n) ? exact[(long)b * ROWCAP + j] : -1e30f;
  __syncthreads();
  // sure-ins inside cand bins
  unsigned loc = 0;
  for (int i = j; i < nc; i += 256) loc += (candv[(long)b * CANDCAP + i] > hi) ? 1u : 0u;
  if (loc) atomicAdd(&s_c, loc);
  __syncthreads();
  const int need = KCNT - (int)c1[b] - (int)s_c;
  // band rank-select -> write winners
  if (j < n) {
    const float vj = vals[j];
    int rank = 0;
    for (int i = 0; i < n; ++i) {
      const float vi = vals[i];
      rank += (vi > vj || (vi == vj && i < j)) ? 1 : 0;
    }
    if (rank < need)
      a1[(long)b * NROWS_W + rowlist[(long)b * ROWCAP + j]] = (_Float16)vals[j];
  }
  // patch cand sure-ins (placeholder 0 -> stored fp16 value)
  for (int i = j; i < nc; i += 256) {
    const float v = candv[(long)b * CANDCAP + i];
    if (v > hi) a1[(long)b * NROWS_W + candi[(long)b * CANDCAP + i]] = (_Float16)v;
  }
}

extern "C" void kernel_launch(void* const* d_in, const int* in_sizes, int n_in,
                              void* d_out, int out_size, void* d_ws, size_t ws_size,
                              hipStream_t stream) {
  const float* x     = (const float*)d_in[0];
  const float* W     = (const float*)d_in[1];
  const float* b_enc = (const float*)d_in[2];
  const float* b_dec = (const float*)d_in[3];
  float* out = (float*)d_out;

  const long NW = (long)NROWS_W * DIM;    // 134217728
  const long NX = (long)BATCH * DIM;      // 16777216
  const long NZ = (long)BATCH * NROWS_W;  // 134217728

  char* ws = (char*)d_ws;
  _Float16* Wh = (_Float16*)ws;     // 2*NW (dead after encoder -> reused as a1)
  _Float16* Wt = Wh + NW;           // 2*NW
  _Float16* xh = Wt + NW;           // 2*NX
  _Float16* z1f = xh + NX;          // 2*NZ (fp16 z1)
  float*  thr = (float*)(z1f + NZ); // 4*BATCH
  char*   sc = (char*)(thr + BATCH);
  unsigned* rowcnt  = (unsigned*)sc;                     // 16 KB
  unsigned* c1      = (unsigned*)(sc + 16384);           // 16 KB
  unsigned* bcnt    = (unsigned*)(sc + 32768);           // 128 KB (zeroed in splitw)
  float*    exact   = (float*)(sc + 163840);             // 4 MB
  unsigned* rowlist = (unsigned*)(sc + 4358144);         // 4 MB
  unsigned* bucket  = (unsigned*)(sc + 8552448);         // 8 MB
  unsigned* candn   = (unsigned*)(sc + 16941056);        // 16 KB
  float*    candv   = (float*)(sc + 16957440);           // 8.4 MB
  unsigned short* candi = (unsigned short*)(sc + 25346048);  // 4.2 MB -> end 29.5 MB
  _Float16* a1 = Wh;

  const size_t needed = (size_t)(4 * NW + 2 * NX + 2 * NZ) + 4 * BATCH + 29540352;
  if (ws_size < needed) return;

  k_splitw<<<dim3(DIM / 64, NROWS_W / 64), dim3(64, 8), 0, stream>>>(W, Wh, Wt, (f32x4*)bcnt);
  k_cvtx<<<2048, 256, 0, stream>>>(x, xh, (int)(NX / 4));

  // encoder (approx): z1 = xh @ Wh^T + b_enc -> fp16; supertile 16x32
  k_gemm<BATCH, NROWS_W, DIM, 4, 5, _Float16>
      <<<(BATCH / 128) * (NROWS_W / 128), 256, 0, stream>>>(xh, Wh, b_enc, z1f);

  k_topk16<<<BATCH, 256, 0, stream>>>((const unsigned short*)z1f, thr, rowlist,
                                      rowcnt, c1, bucket, bcnt,
                                      (unsigned short*)a1, candv, candi, candn, KCNT);
  k_recompute<<<NROWS_W, 256, 0, stream>>>(W, x, b_enc, bucket, bcnt, exact);
  k_select<<<BATCH, ROWCAP, 0, stream>>>(exact, rowlist, rowcnt, c1, thr,
                                         candv, candi, candn, a1);

  // decoder: out = a1 @ W + b_dec (B^T = Wt); supertile 16x32 (measured best)
  k_gemm<BATCH, DIM, NROWS_W, 4, 5, float>
      <<<(BATCH / 128) * (DIM / 128), 256, 0, stream>>>(a1, Wt, b_dec, out);
}

// Round 15
// 2913.484 us; speedup vs baseline: 1.1782x; 1.0245x over previous
//
#include <hip/hip_runtime.h>
#include <hip/hip_bf16.h>
#include <hip/hip_fp16.h>
#include <stdint.h>

// Sparse autoencoder: z1 = x@W^T + b_enc ; top-k(3276) mask ; z2 = a1@W + b_dec
// Encoder = single fp16 MFMA GEMM writing fp16 z1; exact top-k selection via
// fp32 band recompute near the exact k-th fp16 threshold (h-major, W streamed
// once, fp32 x L3-resident). GEMMs: proven 128^2 m97-structure + T2 swizzle +
// 16x32 supertile remap on RAW blockIdx for BOTH GEMMs (measured best across
// R10-R14). splitw fully vectorized (f32x4 read, f16x4/f16x8 writes).

#define DIM      4096
#define BATCH    4096
#define NROWS_W  32768
#define KCNT     3276
#define DELTA    0.003f
#define ROWCAP   256
#define HCAP     64
#define CANDCAP  512

typedef _Float16 f16x8 __attribute__((ext_vector_type(8)));
typedef _Float16 f16x4 __attribute__((ext_vector_type(4)));
typedef float    f32x4 __attribute__((ext_vector_type(4)));
typedef unsigned short u16x8 __attribute__((ext_vector_type(8)));

__device__ __forceinline__ void gload_lds16(const void* g, void* l) {
  __builtin_amdgcn_global_load_lds(
      (const __attribute__((address_space(1))) void*)g,
      (__attribute__((address_space(3))) void*)l, 16, 0, 0);
}

// ---------------- x: fp32 -> fp16 (encoder A operand) ----------------
__global__ void k_cvtx(const float* __restrict__ s, _Float16* __restrict__ hi, int n4) {
  int i = blockIdx.x * 256 + threadIdx.x;
  const int stride = gridDim.x * 256;
  for (; i < n4; i += stride) {
    f32x4 v = ((const f32x4*)s)[i];
    f16x4 h;
#pragma unroll
    for (int j = 0; j < 4; ++j) h[j] = (_Float16)v[j];
    ((f16x4*)hi)[i] = h;
  }
}

// --- fused W convert+transpose: W fp32 -> Wh fp16 [H,D] + Wt fp16 [D,H] ------
// Vectorized: f32x4 loads, f16x4 Wh stores, f16x8 Wt stores. 64x64 tile,
// 256 threads. LDS pad 65 -> stage-2 gather is 2 lanes/bank (free, G4).
// Also zeroes bcnt (blockIdx.y==0 blocks) to save a launch.
__global__ __launch_bounds__(256)
void k_splitw(const float* __restrict__ W, _Float16* __restrict__ Wh,
              _Float16* __restrict__ Wt, f32x4* __restrict__ bcntv) {
  __shared__ _Float16 ts[64][65];
  const int c0 = blockIdx.x * 64, r0 = blockIdx.y * 64;
  const int tid = threadIdx.x;
  if (blockIdx.y == 0) {
    const int idx = blockIdx.x * 256 + tid;
    if (idx < 8192) {  // 128 KB bcnt
      f32x4 z = {0.f, 0.f, 0.f, 0.f};
      bcntv[idx] = z;
    }
  }
#pragma unroll
  for (int it = 0; it < 4; ++it) {
    const int q = it * 256 + tid;
    const int row = q >> 4, seg = q & 15;  // 64 rows x 16 f32x4-segs
    const f32x4 v = *(const f32x4*)(W + (long)(r0 + row) * DIM + c0 + seg * 4);
    f16x4 h;
#pragma unroll
    for (int j = 0; j < 4; ++j) h[j] = (_Float16)v[j];
    *(f16x4*)(Wh + (long)(r0 + row) * DIM + c0 + seg * 4) = h;
#pragma unroll
    for (int j = 0; j < 4; ++j) ts[row][seg * 4 + j] = h[j];
  }
  __syncthreads();
#pragma unroll
  for (int it = 0; it < 2; ++it) {
    const int q = it * 256 + tid;
    const int col = q >> 3, seg = q & 7;   // 64 cols x 8 f16x8-segs
    f16x8 v;
#pragma unroll
    for (int j = 0; j < 8; ++j) v[j] = ts[seg * 8 + j][col];
    *(f16x8*)(Wt + (long)(c0 + col) * NROWS_W + r0 + seg * 8) = v;
  }
}

// ---------------- GEMM: C[M,N] = A[M,K] * B^T[N,K] + bias (proven R10) -------
// T2 XOR-swizzled LDS; (2^SML x 2^SNL) supertile remap on raw blockIdx.
template <int MT, int NTOT, int KT, int SML, int SNL, typename OutT>
__global__ __launch_bounds__(256, 2)
void k_gemm(const _Float16* __restrict__ A, const _Float16* __restrict__ B,
            const float* __restrict__ bias, OutT* __restrict__ C) {
  constexpr int BM = 128, BN = 128, BK = 64;
  __shared__ __align__(16) _Float16 sA[BM * BK];
  __shared__ __align__(16) _Float16 sB[BN * BK];

  const int tid = threadIdx.x;
  constexpr int nbn = NTOT / BN;
  constexpr int nstn = nbn >> SNL;
  constexpr int stsz = 1 << (SML + SNL);

  const int g = blockIdx.x >> (SML + SNL), r = blockIdx.x & (stsz - 1);
  const int bm = ((g / nstn) << SML) + (r >> SNL);
  const int bn = ((g % nstn) << SNL) + (r & ((1 << SNL) - 1));

  const int m0 = bm * BM, n0 = bn * BN;
  const int lane = tid & 63, wid = tid >> 6;
  const int wm = wid >> 1, wn = wid & 1;
  const int lr = lane & 15, lk = lane >> 4;
  const int swz = (lr & 7) << 4;

  f32x4 acc[4][4] = {};

  for (int k0 = 0; k0 < KT; k0 += BK) {
#pragma unroll
    for (int rr = 0; rr < 4; ++rr) {
      const int o = (rr * 256 + tid) * 16;
      const int row = o >> 7;
      const int colb = (o & 127) ^ ((row & 7) << 4);
      const long gA = ((long)(m0 + row) * KT + k0) * 2 + colb;
      const long gB = ((long)(n0 + row) * KT + k0) * 2 + colb;
      gload_lds16((const char*)A + gA, (char*)sA + o);
      gload_lds16((const char*)B + gB, (char*)sB + o);
    }
    __syncthreads();

#pragma unroll
    for (int kk = 0; kk < 2; ++kk) {
      f16x8 va[4], vb[4];
      const int kbase = (kk * 64 + lk * 16) ^ swz;
#pragma unroll
      for (int m = 0; m < 4; ++m) {
        const int row = wm * 64 + m * 16 + lr;
        va[m] = *(const f16x8*)((const char*)sA + row * 128 + kbase);
      }
#pragma unroll
      for (int n = 0; n < 4; ++n) {
        const int row = wn * 64 + n * 16 + lr;
        vb[n] = *(const f16x8*)((const char*)sB + row * 128 + kbase);
      }
#pragma unroll
      for (int m = 0; m < 4; ++m)
#pragma unroll
        for (int n = 0; n < 4; ++n)
          acc[m][n] = __builtin_amdgcn_mfma_f32_16x16x32_f16(va[m], vb[n], acc[m][n], 0, 0, 0);
    }
    __syncthreads();
  }

  // C/D layout: col = lane&15, row = (lane>>4)*4 + reg
#pragma unroll
  for (int n = 0; n < 4; ++n) {
    const int col = n0 + wn * 64 + n * 16 + lr;
    const float bv = bias[col];
#pragma unroll
    for (int m = 0; m < 4; ++m) {
      const int r0r = m0 + wm * 64 + m * 16 + lk * 4;
#pragma unroll
      for (int j = 0; j < 4; ++j)
        C[(long)(r0r + j) * NTOT + col] = (OutT)(acc[m][n][j] + bv);
    }
  }
}

// ------------- fp16 bits <-> order-preserving 16-bit key ----------------
__device__ __forceinline__ unsigned f2o16(unsigned b) {
  return (b & 0x8000u) ? (~b & 0xFFFFu) : (b | 0x8000u);
}
__device__ __forceinline__ float o2f16v(unsigned key) {
  const unsigned short bb = (key & 0x8000u) ? (unsigned short)(key & 0x7FFFu)
                                            : (unsigned short)(~key & 0xFFFFu);
  return (float)__builtin_bit_cast(_Float16, bb);
}

// --- per-row: exact k-th fp16 threshold + band + bulk a1 write (2 streams) ---
__global__ __launch_bounds__(256)
void k_topk16(const unsigned short* __restrict__ z1b, float* __restrict__ thr,
              unsigned* __restrict__ rowlist, unsigned* __restrict__ rowcnt,
              unsigned* __restrict__ c1, unsigned* __restrict__ bucket,
              unsigned* __restrict__ bcnt, unsigned short* __restrict__ a1b,
              float* __restrict__ candv, unsigned short* __restrict__ candi,
              unsigned* __restrict__ candn, int kwant) {
  __shared__ unsigned hist[4096];
  __shared__ float cv[CANDCAP];
  __shared__ unsigned short ci[CANDCAP];
  __shared__ unsigned s_n, s_bin, s_rem, s_wt[4], s_cnt, s_above;
  const int tid = threadIdx.x;
  const int b = blockIdx.x;
  const u16x8* zv = (const u16x8*)(z1b + (long)b * NROWS_W);
  constexpr int NV = NROWS_W / 8;

  // ---- pass A: 4096-bin histogram on key bits 15:4 ----
#pragma unroll
  for (int j = 0; j < 16; ++j) hist[tid + j * 256] = 0;
  if (tid == 0) { s_n = 0; s_cnt = 0; s_above = 0; }
  __syncthreads();
  for (int i = tid; i < NV; i += 256) {
    u16x8 v = zv[i];
#pragma unroll
    for (int j = 0; j < 8; ++j) atomicAdd(&hist[f2o16(v[j]) >> 4], 1u);
  }
  __syncthreads();
  unsigned p = 0;
#pragma unroll
  for (int j = 0; j < 16; ++j) p += hist[tid * 16 + j];
  unsigned sfx = p;
  const int lane = tid & 63, w = tid >> 6;
#pragma unroll
  for (int off = 1; off < 64; off <<= 1) {
    unsigned o = __shfl_down(sfx, off);
    sfx += (lane + off < 64) ? o : 0u;
  }
  if (lane == 0) s_wt[w] = sfx;
  __syncthreads();
  unsigned above_waves = 0;
  for (int ww = w + 1; ww < 4; ++ww) above_waves += s_wt[ww];
  const unsigned incl = sfx + above_waves;
  const int cnt = __syncthreads_count(incl >= (unsigned)kwant);
  const int tstar = cnt - 1;
  if (tid == tstar) {
    unsigned cum = incl - p;
    int bsel = tid * 16;
    for (int j = 15; j >= 0; --j) {
      const unsigned h = hist[tid * 16 + j];
      if (cum + h >= (unsigned)kwant) { bsel = tid * 16 + j; break; }
      cum += h;
    }
    s_bin = (unsigned)bsel;
    s_rem = (unsigned)kwant - cum;
  }
  __syncthreads();
  const unsigned binsel = s_bin;
  const unsigned rem = s_rem;

  // c_above: bins >= binsel+2 are all > t+DELTA (bin width = 16 ulp >= 0.0078
  // at t~1.3 > DELTA)
  {
    unsigned loc = 0;
#pragma unroll
    for (int j = 0; j < 16; ++j) {
      const unsigned bin = tid * 16 + j;
      if (bin >= binsel + 2) loc += hist[bin];
    }
    if (loc) atomicAdd(&s_above, loc);
  }

  // ---- pass B: bulk a1 write + cand collect (bins binsel-1..binsel+1) ----
  const unsigned blo = (binsel > 0) ? binsel - 1 : 0;
  const unsigned bhi = binsel + 1;
  u16x8* av = (u16x8*)(a1b + (long)b * NROWS_W);
  for (int i = tid; i < NV; i += 256) {
    u16x8 v = zv[i];
    u16x8 o;
#pragma unroll
    for (int j = 0; j < 8; ++j) {
      const unsigned bits = v[j];
      const unsigned bin = f2o16(bits) >> 4;
      o[j] = (bin > bhi) ? (unsigned short)bits : (unsigned short)0;
      if (bin >= blo && bin <= bhi) {
        const unsigned jj = atomicAdd(&s_n, 1u);
        if (jj < CANDCAP) {
          cv[jj] = (float)__builtin_bit_cast(_Float16, (unsigned short)bits);
          ci[jj] = (unsigned short)(i * 8 + j);
        }
      }
    }
    av[i] = o;
  }
  __syncthreads();
  const int n = (s_n < CANDCAP) ? (int)s_n : CANDCAP;
  if (tid == 0) candn[b] = (unsigned)n;
  if (tid < 16) hist[tid] = 0;
  __syncthreads();

  // mirror cands to global + refine histogram (low 4 key bits, binsel only)
  for (int i = tid; i < n; i += 256) {
    const float v = cv[i];
    candv[(long)b * CANDCAP + i] = v;
    candi[(long)b * CANDCAP + i] = ci[i];
    const unsigned short bb = __builtin_bit_cast(unsigned short, (_Float16)v);
    const unsigned key = f2o16(bb);
    if ((key >> 4) == binsel) atomicAdd(&hist[key & 15u], 1u);
  }
  __syncthreads();
  if (tid == 0) {
    unsigned cum = 0;
    int d = 15;
    for (; d > 0; --d) {
      if (cum + hist[d] >= rem) break;
      cum += hist[d];
    }
    s_bin = (unsigned)d;
  }
  __syncthreads();
  const float t = o2f16v((binsel << 4) | s_bin);  // exact k-th largest fp16
  if (tid == 0) thr[b] = t;
  const float hi = t + DELTA, lo = t - DELTA;

  // ---- band members from LDS cand list ----
  for (int i = tid; i < n; i += 256) {
    const float v = cv[i];
    if (v >= lo && v <= hi) {
      const unsigned idx = ci[i];
      const unsigned jj = atomicAdd(&s_cnt, 1u);
      if (jj < ROWCAP) {
        rowlist[(long)b * ROWCAP + jj] = idx;
        const unsigned pq = atomicAdd(&bcnt[idx], 1u);
        if (pq < HCAP) bucket[(long)idx * HCAP + pq] = ((unsigned)b << 9) | jj;
      }
    }
  }
  __syncthreads();
  if (tid == 0) {
    rowcnt[b] = (s_cnt < ROWCAP) ? s_cnt : ROWCAP;
    c1[b] = s_above;  // sure-ins OUTSIDE cand bins
  }
}

// -------- h-major exact recompute: fp32 W row in LDS, fp32 x (L3) ----------
__global__ void k_recompute(const float* __restrict__ W, const float* __restrict__ x,
                            const float* __restrict__ b_enc,
                            const unsigned* __restrict__ bucket,
                            const unsigned* __restrict__ bcnt,
                            float* __restrict__ exact) {
  const int h = blockIdx.x;
  unsigned n = bcnt[h];
  if (n > HCAP) n = HCAP;
  if (n == 0) return;
  __shared__ float wrec[DIM];
  const long wb = (long)h * DIM;
  for (int i = threadIdx.x; i < DIM / 4; i += 256)
    ((f32x4*)wrec)[i] = ((const f32x4*)(W + wb))[i];
  __syncthreads();
  const float be = b_enc[h];
  const int w = threadIdx.x >> 6, lane = threadIdx.x & 63;
  for (unsigned e = w; e < n; e += 4) {
    const unsigned ent = bucket[(long)h * HCAP + e];
    const int b = ent >> 9, j = ent & 511;
    const f32x4* xv = (const f32x4*)(x + (long)b * DIM);
    float s = 0.f;
#pragma unroll
    for (int c = 0; c < 16; ++c) {
      const int i4 = c * 64 + lane;
      f32x4 v = xv[i4];
      const float* wr = &wrec[i4 * 4];
#pragma unroll
      for (int q = 0; q < 4; ++q) s += v[q] * wr[q];
    }
#pragma unroll
    for (int m = 32; m; m >>= 1) s += __shfl_xor(s, m);
    if (lane == 0) exact[(long)b * ROWCAP + j] = s + be;
  }
}

// -- per-row: finalize counts, band rank-select, patch cand region of a1 -----
__global__ void k_select(const float* __restrict__ exact, const unsigned* __restrict__ rowlist,
                         const unsigned* __restrict__ rowcnt, const unsigned* __restrict__ c1,
                         const float* __restrict__ thr, const float* __restrict__ candv,
                         const unsigned short* __restrict__ candi,
                         const unsigned* __restrict__ candn,
                         _Float16* __restrict__ a1) {
  const int b = blockIdx.x;
  const int n = (int)rowcnt[b];
  const int nc = (int)candn[b];
  const float t = thr[b];
  const float hi = t + DELTA;
  __shared__ float vals[ROWCAP];
  __shared__ unsigned s_c;
  const int j = threadIdx.x;  // blockDim == ROWCAP == 256
  if (j == 0) s_c = 0;
  vals[j] = (j < n) ? exact[(long)b * ROWCAP + j] : -1e30f;
  __syncthreads();
  // sure-ins inside cand bins
  unsigned loc = 0;
  for (int i = j; i < nc; i += 256) loc += (candv[(long)b * CANDCAP + i] > hi) ? 1u : 0u;
  if (loc) atomicAdd(&s_c, loc);
  __syncthreads();
  const int need = KCNT - (int)c1[b] - (int)s_c;
  // band rank-select -> write winners
  if (j < n) {
    const float vj = vals[j];
    int rank = 0;
    for (int i = 0; i < n; ++i) {
      const float vi = vals[i];
      rank += (vi > vj || (vi == vj && i < j)) ? 1 : 0;
    }
    if (rank < need)
      a1[(long)b * NROWS_W + rowlist[(long)b * ROWCAP + j]] = (_Float16)vals[j];
  }
  // patch cand sure-ins (placeholder 0 -> stored fp16 value)
  for (int i = j; i < nc; i += 256) {
    const float v = candv[(long)b * CANDCAP + i];
    if (v > hi) a1[(long)b * NROWS_W + candi[(long)b * CANDCAP + i]] = (_Float16)v;
  }
}

extern "C" void kernel_launch(void* const* d_in, const int* in_sizes, int n_in,
                              void* d_out, int out_size, void* d_ws, size_t ws_size,
                              hipStream_t stream) {
  const float* x     = (const float*)d_in[0];
  const float* W     = (const float*)d_in[1];
  const float* b_enc = (const float*)d_in[2];
  const float* b_dec = (const float*)d_in[3];
  float* out = (float*)d_out;

  const long NW = (long)NROWS_W * DIM;    // 134217728
  const long NX = (long)BATCH * DIM;      // 16777216
  const long NZ = (long)BATCH * NROWS_W;  // 134217728

  char* ws = (char*)d_ws;
  _Float16* Wh = (_Float16*)ws;     // 2*NW (dead after encoder -> reused as a1)
  _Float16* Wt = Wh + NW;           // 2*NW
  _Float16* xh = Wt + NW;           // 2*NX
  _Float16* z1f = xh + NX;          // 2*NZ (fp16 z1)
  float*  thr = (float*)(z1f + NZ); // 4*BATCH
  char*   sc = (char*)(thr + BATCH);
  unsigned* rowcnt  = (unsigned*)sc;                     // 16 KB
  unsigned* c1      = (unsigned*)(sc + 16384);           // 16 KB
  unsigned* bcnt    = (unsigned*)(sc + 32768);           // 128 KB (zeroed in splitw)
  float*    exact   = (float*)(sc + 163840);             // 4 MB
  unsigned* rowlist = (unsigned*)(sc + 4358144);         // 4 MB
  unsigned* bucket  = (unsigned*)(sc + 8552448);         // 8 MB
  unsigned* candn   = (unsigned*)(sc + 16941056);        // 16 KB
  float*    candv   = (float*)(sc + 16957440);           // 8.4 MB
  unsigned short* candi = (unsigned short*)(sc + 25346048);  // 4.2 MB -> end 29.5 MB
  _Float16* a1 = Wh;

  const size_t needed = (size_t)(4 * NW + 2 * NX + 2 * NZ) + 4 * BATCH + 29540352;
  if (ws_size < needed) return;

  k_splitw<<<dim3(DIM / 64, NROWS_W / 64), 256, 0, stream>>>(W, Wh, Wt, (f32x4*)bcnt);
  k_cvtx<<<2048, 256, 0, stream>>>(x, xh, (int)(NX / 4));

  // encoder (approx): z1 = xh @ Wh^T + b_enc -> fp16; supertile 16x32
  k_gemm<BATCH, NROWS_W, DIM, 4, 5, _Float16>
      <<<(BATCH / 128) * (NROWS_W / 128), 256, 0, stream>>>(xh, Wh, b_enc, z1f);

  k_topk16<<<BATCH, 256, 0, stream>>>((const unsigned short*)z1f, thr, rowlist,
                                      rowcnt, c1, bucket, bcnt,
                                      (unsigned short*)a1, candv, candi, candn, KCNT);
  k_recompute<<<NROWS_W, 256, 0, stream>>>(W, x, b_enc, bucket, bcnt, exact);
  k_select<<<BATCH, ROWCAP, 0, stream>>>(exact, rowlist, rowcnt, c1, thr,
                                         candv, candi, candn, a1);

  // decoder: out = a1 @ W + b_dec (B^T = Wt); supertile 16x32 (measured best)
  k_gemm<BATCH, DIM, NROWS_W, 4, 5, float>
      <<<(BATCH / 128) * (DIM / 128), 256, 0, stream>>>(a1, Wt, b_dec, out);
}